// Round 8
// baseline (1676.854 us; speedup 1.0000x reference)
//
#include <hip/hip_runtime.h>
#include <hip/hip_bf16.h>
#include <math.h>

#define BB 8
#define LL 64
#define DD 256
#define VV 4096
#define RR 512           // BB*LL
#define K3 768

typedef __attribute__((ext_vector_type(4))) float f32x4;
typedef __attribute__((ext_vector_type(8))) short bf16x8;
typedef __attribute__((ext_vector_type(4))) unsigned short u16x4;
typedef __attribute__((ext_vector_type(8))) unsigned short u16x8;
typedef unsigned long long u64;

// ---- workspace layout (float offsets) -----------------------------------
#define WS_ZE      0
#define WS_ZEU3    (WS_ZE + RR*DD)           // dead after scan
#define WS_WCT     (WS_ZEU3 + RR*DD)         // dead after scan
#define WS_XSA0    (WS_WCT + DD*K3)          // dead after k_sel
#define WS_XSA1    (WS_XSA0 + RR*DD)         // dead after scan
#define WS_EMIT    (WS_XSA1 + RR*DD)
#define WS_YVEC    (WS_EMIT + RR*DD)
#define WS_X0VEC   (WS_YVEC + DD)
#define WS_YK      (WS_X0VEC + DD)
#define WS_YLOG    (WS_YK + DD)
#define WS_YLSE    (WS_YLOG + VV)
#define WS_SEL     (WS_YLSE + 8)
#define WS_LSE     (WS_SEL + RR*4)
#define WS_TGT     (WS_LSE + 1024)
// Sync counters live in the EMIT region: EMIT is written only AFTER the
// scan (k_rowmat2), and k_zero_cnt runs right before the scan. 64 token
// lines + 64 rgdone lines, 128B (32 int) stride each => 16 KB.
#define WS_TOKS    WS_EMIT                   // int tok[64*32]; int rgd[64*32]
// Overlays (regions dead after the scan):
#define WS_HPART   WS_WCT                    // 1024*64*2 = 131072 <= 196608
#define WS_UHI     WS_ZEU3
#define WS_ULO     WS_XSA1
// MFMA-only tail:
#define WS_EHI     861184
#define WS_ELO     (WS_EHI + VV*DD/2)
#define WS_TOTAL_MFMA (WS_ELO + VV*DD/2)     // 7,639,040 bytes

__device__ __forceinline__ float waveSum(float v) {
#pragma unroll
  for (int o = 32; o > 0; o >>= 1) v += __shfl_xor(v, o, 64);
  return v;
}

__device__ __forceinline__ float blockSum256(float v) {
  __shared__ float red[4];
  int lane = threadIdx.x & 63, w = threadIdx.x >> 6;
  v = waveSum(v);
  __syncthreads();
  if (lane == 0) red[w] = v;
  __syncthreads();
  return red[0] + red[1] + red[2] + red[3];
}

__device__ __forceinline__ unsigned short f2bf(float f) {
  unsigned int u = __float_as_uint(f);
  unsigned int r = (u + 0x7fffu + ((u >> 16) & 1u)) >> 16;
  return (unsigned short)r;
}
__device__ __forceinline__ float bf2f(unsigned short h) {
  return __uint_as_float(((unsigned int)h) << 16);
}

union U64F2 { u64 u; float f[2]; };

// --- normalize rows: ze (512), yvec, x0vec -------------------------------
__global__ __launch_bounds__(256) void k_norm_rows(
    const int* __restrict__ z, const float* __restrict__ embed,
    const float* __restrict__ initw, float* __restrict__ ws) {
  int r = blockIdx.x, d = threadIdx.x;
  float a; float* dst;
  if (r < RR) { int tok = z[r]; a = embed[tok * DD + d]; dst = ws + WS_ZE + r * DD; }
  else if (r == RR) { a = embed[d]; dst = ws + WS_YVEC; }
  else { a = initw[d * 16]; dst = ws + WS_X0VEC; }
  float s  = blockSum256(a);
  float sq = blockSum256(a * a);
  float mean = s * (1.0f / DD);
  float var = fmaxf((sq - (float)DD * mean * mean) * (1.0f / (DD - 1)), 0.0f);
  dst[d] = a / (1e-5f + sqrtf(var));
}

// --- build combined transposed weights WcT[c][0:768] = [Tw;TwT;Cw]/3 -----
__global__ __launch_bounds__(256) void k_build_w(
    const float* __restrict__ tw, const float* __restrict__ cw,
    float* __restrict__ wct) {
  int c = blockIdx.x, k = threadIdx.x;
  const float inv3 = 1.0f / 3.0f;
  wct[c * K3 + k]       = tw[k * DD + c] * inv3;  // x[l-1] @ Tw
  wct[c * K3 + 256 + k] = tw[c * DD + k] * inv3;  // x[l+1] @ Tw^T
  wct[c * K3 + 512 + k] = cw[k * DD + c] * inv3;  // x[l]   @ Cw
}

// --- yk = yvec @ xkd_w^T + xkd_b -----------------------------------------
__global__ __launch_bounds__(256) void k_yk(
    const float* __restrict__ xkdw, const float* __restrict__ xkdb,
    float* __restrict__ ws) {
  int d = threadIdx.x;
  __shared__ float y[DD];
  y[d] = ws[WS_YVEC + d];
  __syncthreads();
  float acc = xkdb[d];
  for (int k = 0; k < DD; k++) acc += y[k] * xkdw[d * DD + k];
  ws[WS_YK + d] = acc;
}

// --- broadcast x0vec into xsa buffer 0 -----------------------------------
__global__ __launch_bounds__(256) void k_bcast(float* __restrict__ ws) {
  int r = blockIdx.x, d = threadIdx.x;
  ws[WS_XSA0 + r * DD + d] = ws[WS_X0VEC + d];
}

// --- out[r][d] = scale*(in[r]·W[d,:] + bias[d]) ; 2 rows / block ----------
__global__ __launch_bounds__(256) void k_rowmat2(
    const float* __restrict__ in, const float* __restrict__ W,
    const float* __restrict__ bias, float* __restrict__ out, float scale) {
  int r0 = blockIdx.x * 2, d = threadIdx.x;
  __shared__ float u[2][260];
  u[0][d] = in[r0 * DD + d];
  u[1][d] = in[(r0 + 1) * DD + d];
  __syncthreads();
  float a0 = 0.f, a1 = 0.f;
  const float4* w4 = (const float4*)(W + d * DD);
  const float4* u0 = (const float4*)&u[0][0];
  const float4* u1 = (const float4*)&u[1][0];
#pragma unroll 8
  for (int k4 = 0; k4 < 64; k4++) {
    float4 w = w4[k4], x0 = u0[k4], x1 = u1[k4];
    a0 += x0.x*w.x + x0.y*w.y + x0.z*w.z + x0.w*w.w;
    a1 += x1.x*w.x + x1.y*w.y + x1.z*w.z + x1.w*w.w;
  }
  float b = bias[d];
  out[r0 * DD + d]       = (a0 + b) * scale;
  out[(r0 + 1) * DD + d] = (a1 + b) * scale;
}

// --- zero the padded sync counters (each replay): 4096 ints --------------
__global__ void k_zero_cnt(int* __restrict__ c) {
  c[blockIdx.x * 256 + threadIdx.x] = 0;
}

// --- persistent cooperative scan: all 64 steps in one kernel -------------
// 512 blocks (2/CU), 256 thr. Block = 8 rows x 32 cols. W in VGPRs (once).
// Data exchange via RELAXED agent-scope bypass atomics (R7-proven).
// R8 sync overhaul: (1) counters padded to one 128B line per rowgroup
// (R7 had 512 RMWs/step on ONE line -> L3 convoy); (2) two-level
// completion: 8 sibling tok adds -> one rgdone publish; (3) wave-0
// vector poll: one load covers all 3 neighbor lines per round.
__global__ __launch_bounds__(256, 2) void k_scan(float* __restrict__ ws) {
  const int bid = blockIdx.x;
  const int rg = bid & 63, cg = bid >> 6;   // siblings (same rg) share XCD
  const int b = rg >> 3, rgl = rg & 7, l0 = rgl * 8;
  const int t = threadIdx.x;
  const int cl = t & 7, rs = t >> 3;
  const int c0 = cg * 32 + cl * 4;

  __shared__ float S[10 * 264];     // staged x rows l0-1..l0+8
  __shared__ float PAR[32 * 260];   // split-K partials
  __shared__ float PAR2[4 * 256];
  __shared__ float ZB[256];         // zeu3 tile (step-invariant)

  const float* wct  = ws + WS_WCT;
  const float* zeu3 = ws + WS_ZEU3;
  int* tok = (int*)(ws + WS_TOKS);          // tok[rg] at tok + rg*32
  int* rgd = tok + 64 * 32;                 // rgd[rg] at rgd + rg*32

  // ---- W into registers: 4 cols x 3 parts x 8 k = 96 floats (static idx)
  float4 wreg[24];
#pragma unroll
  for (int p = 0; p < 3; ++p)
#pragma unroll
    for (int q = 0; q < 2; ++q)
#pragma unroll
      for (int c4 = 0; c4 < 4; ++c4)
        wreg[(p * 2 + q) * 4 + c4] =
            *(const float4*)&wct[(size_t)(c0 + c4) * K3 + p * 256 + rs * 8 + q * 4];

  { // zeu3 tile
    int r = t >> 5, c = t & 31;
    ZB[r * 32 + c] = zeu3[(size_t)(b * 64 + l0 + r) * DD + cg * 32 + c];
  }

  const int nb0 = b * 8 + ((rgl + 7) & 7);  // prev rowgroup
  const int nb1 = b * 8 + rgl;              // own
  const int nb2 = b * 8 + ((rgl + 1) & 7);  // next

  // per-lane poll target (wave 0 only): lanes 0,1,2 -> nb0,nb1,nb2
  const int mynb = (t == 0) ? nb0 : (t == 1) ? nb1 : nb2;

  for (int st = 0; st < 64; ++st) {
    const float* xin  = ws + ((st & 1) ? WS_XSA1 : WS_XSA0);
    float*       xout = ws + ((st & 1) ? WS_XSA0 : WS_XSA1);

    if (st > 0) {
      if (t < 64) {   // wave 0: vector poll of 3 rgdone lines, one load/round
        while (true) {
          int v = __hip_atomic_load(rgd + mynb * 32, __ATOMIC_RELAXED,
                                    __HIP_MEMORY_SCOPE_AGENT);
          if (__all(v >= st)) break;
          __builtin_amdgcn_s_sleep(1);
        }
      }
      __syncthreads();
    }

    // stage 10 rows x 256 f via bypass u64 loads: 5 per thread
#pragma unroll
    for (int it = 0; it < 5; ++it) {
      int idx = it * 256 + t;
      int j = idx >> 7;               // row 0..9
      int kk = (idx & 127) << 1;      // float offset 0..254
      int l = (l0 + j - 1 + 64) & 63;
      u64 v = __hip_atomic_load(
          (const u64*)(xin + (size_t)(b * 64 + l) * DD + kk),
          __ATOMIC_RELAXED, __HIP_MEMORY_SCOPE_AGENT);
      *(u64*)(&S[j * 264 + kk]) = v;
    }
    __syncthreads();

    float acc[8][4];
#pragma unroll
    for (int r = 0; r < 8; ++r)
#pragma unroll
      for (int c4 = 0; c4 < 4; ++c4) acc[r][c4] = 0.f;

#pragma unroll
    for (int p = 0; p < 3; ++p) {
      const int jof = (p == 0) ? 0 : (p == 1) ? 2 : 1;
#pragma unroll
      for (int r = 0; r < 8; ++r) {
#pragma unroll
        for (int q = 0; q < 2; ++q) {
          float4 x = *(const float4*)&S[(r + jof) * 264 + rs * 8 + q * 4];
#pragma unroll
          for (int c4 = 0; c4 < 4; ++c4) {
            float4 w = wreg[(p * 2 + q) * 4 + c4];
            acc[r][c4] += x.x * w.x + x.y * w.y + x.z * w.z + x.w * w.w;
          }
        }
      }
    }

    // partials -> LDS
#pragma unroll
    for (int r = 0; r < 8; ++r) {
      float4 v4 = {acc[r][0], acc[r][1], acc[r][2], acc[r][3]};
      *(float4*)&PAR[rs * 260 + r * 32 + cl * 4] = v4;
    }
    __syncthreads();

    { // reduce 32 -> 4
      int u = t & 63, v = t >> 6;
      float4 s4 = {0.f, 0.f, 0.f, 0.f};
#pragma unroll
      for (int i = 0; i < 8; ++i) {
        float4 p4 = *(const float4*)&PAR[(v * 8 + i) * 260 + u * 4];
        s4.x += p4.x; s4.y += p4.y; s4.z += p4.z; s4.w += p4.w;
      }
      *(float4*)&PAR2[v * 256 + u * 4] = s4;
    }
    __syncthreads();

    if (t < 64) { // reduce 4 -> 1, add zeu3, bypass store (2 x u64)
      int r = t >> 3, c8 = t & 7;
      float4 s4 = {0.f, 0.f, 0.f, 0.f};
#pragma unroll
      for (int v = 0; v < 4; ++v) {
        float4 p4 = *(const float4*)&PAR2[v * 256 + t * 4];
        s4.x += p4.x; s4.y += p4.y; s4.z += p4.z; s4.w += p4.w;
      }
      float4 zb = *(const float4*)&ZB[r * 32 + c8 * 4];
      s4.x += zb.x; s4.y += zb.y; s4.z += zb.z; s4.w += zb.w;
      size_t off = (size_t)(b * 64 + l0 + r) * DD + cg * 32 + c8 * 4;
      U64F2 lo, hi;
      lo.f[0] = s4.x; lo.f[1] = s4.y;
      hi.f[0] = s4.z; hi.f[1] = s4.w;
      __hip_atomic_store((u64*)(xout + off),     lo.u, __ATOMIC_RELAXED, __HIP_MEMORY_SCOPE_AGENT);
      __hip_atomic_store((u64*)(xout + off + 2), hi.u, __ATOMIC_RELAXED, __HIP_MEMORY_SCOPE_AGENT);
    }

    // syncthreads drains vmcnt(0): all bypass stores globally visible
    // before the token; the 8th finisher publishes rgdone = st+1.
    __syncthreads();
    if (t == 0) {
      int old = __hip_atomic_fetch_add(tok + nb1 * 32, 1, __ATOMIC_RELAXED,
                                       __HIP_MEMORY_SCOPE_AGENT);
      if ((old & 7) == 7)
        __hip_atomic_store(rgd + nb1 * 32, (old >> 3) + 1, __ATOMIC_RELAXED,
                           __HIP_MEMORY_SCOPE_AGENT);
    }
  }
}

// --- fallback single step (used only if cooperative launch fails) --------
__global__ __launch_bounds__(256) void k_step(
    const float* __restrict__ xin, const float* __restrict__ wct,
    const float* __restrict__ zeu3, float* __restrict__ xout) {
  int rg = blockIdx.x, cg = blockIdx.y;
  int b = rg >> 2, l0 = (rg & 3) * 16;
  int t = threadIdx.x, cl = t & 31, rs = t >> 5;
  int c = cg * 32 + cl;
  __shared__ float S[18][260];
  const float* xb = xin + b * LL * DD;
  for (int j = 0; j < 18; ++j) {
    int l = (l0 + j - 1 + LL) & (LL - 1);
    S[j][t] = xb[l * DD + t];
  }
  __syncthreads();
  float a0 = 0.f, a1 = 0.f;
  const float* wb = wct + c * K3;
#pragma unroll
  for (int p = 0; p < 3; ++p) {
    int j0 = rs + ((p == 0) ? 0 : (p == 1) ? 2 : 1);
    const float4* w4 = (const float4*)(wb + p * 256);
    const float4* u0 = (const float4*)&S[j0][0];
    const float4* u1 = (const float4*)&S[j0 + 8][0];
#pragma unroll 8
    for (int k4 = 0; k4 < 64; ++k4) {
      float4 w = w4[k4], x0 = u0[k4], x1 = u1[k4];
      a0 += x0.x*w.x + x0.y*w.y + x0.z*w.z + x0.w*w.w;
      a1 += x1.x*w.x + x1.y*w.y + x1.z*w.z + x1.w*w.w;
    }
  }
  int r0 = b * LL + l0 + rs;
  int r1 = r0 + 8;
  xout[r0 * DD + c] = a0 + zeu3[r0 * DD + c];
  xout[r1 * DD + c] = a1 + zeu3[r1 * DD + c];
}

// --- split embed into bf16 hi/lo (MFMA path only) ------------------------
__global__ __launch_bounds__(256) void k_split_e(
    const float* __restrict__ e, unsigned short* __restrict__ eh,
    unsigned short* __restrict__ el) {
  int i = (blockIdx.x * 256 + threadIdx.x) * 4;
  float4 v = *(const float4*)(e + i);
  float f[4] = {v.x, v.y, v.z, v.w};
  u16x4 h, l;
#pragma unroll
  for (int j = 0; j < 4; ++j) {
    unsigned short hb = f2bf(f[j]);
    h[j] = hb;
    l[j] = f2bf(f[j] - bf2f(hb));
  }
  *(u16x4*)(eh + i) = h;
  *(u16x4*)(el + i) = l;
}

// --- split U = [emit ; ze] into bf16 hi/lo (MFMA path only) --------------
__global__ __launch_bounds__(256) void k_split_u(float* __restrict__ ws) {
  int row = blockIdx.x, d = threadIdx.x;
  float v = (row < RR) ? ws[WS_EMIT + row * DD + d]
                       : ws[WS_ZE + (row - RR) * DD + d];
  unsigned short hb = f2bf(v);
  unsigned short lb = f2bf(v - bf2f(hb));
  ((unsigned short*)(ws + WS_UHI))[row * DD + d] = hb;
  ((unsigned short*)(ws + WS_ULO))[row * DD + d] = lb;
}

// --- head GEMM via MFMA, split-precision bf16, fused online LSE ----------
// grid (32 rowgroups of 32, 32 vchunks of 128), 256 thr = 4 waves.
__global__ __launch_bounds__(256) void k_head_mfma(
    const unsigned short* __restrict__ uh, const unsigned short* __restrict__ ul,
    const unsigned short* __restrict__ eh, const unsigned short* __restrict__ el,
    float* __restrict__ hpart) {
  int row0 = blockIdx.x * 32;
  int v0 = blockIdx.y * 128;
  int t = threadIdx.x, lane = t & 63, w = t >> 6;
  int wr = w >> 1, wc = w & 1;
  __shared__ unsigned short UH[32 * 264];
  __shared__ unsigned short UL[32 * 264];
#pragma unroll
  for (int it = 0; it < 4; ++it) {
    int r = it * 8 + (t >> 5);
    int c8 = (t & 31) * 8;
    *(u16x8*)(&UH[r * 264 + c8]) = *(const u16x8*)(uh + (row0 + r) * DD + c8);
    *(u16x8*)(&UL[r * 264 + c8]) = *(const u16x8*)(ul + (row0 + r) * DD + c8);
  }
  __syncthreads();

  f32x4 acc[4];
#pragma unroll
  for (int q = 0; q < 4; ++q) acc[q] = (f32x4){0.f, 0.f, 0.f, 0.f};

  int arow = wr * 16 + (lane & 15);
  int kof = 8 * (lane >> 4);
  const unsigned short* Ah = &UH[arow * 264 + kof];
  const unsigned short* Al = &UL[arow * 264 + kof];
  int vbase = v0 + wc * 64 + (lane & 15);

#pragma unroll
  for (int p = 0; p < 3; ++p) {
    const unsigned short* Ab = (p == 2) ? Al : Ah;
    const unsigned short* Ebl = ((p == 1) ? el : eh) + (size_t)vbase * DD + kof;
#pragma unroll
    for (int ks = 0; ks < 8; ++ks) {
      int k0 = ks * 32;
      bf16x8 a = *(const bf16x8*)(Ab + k0);
#pragma unroll
      for (int vt = 0; vt < 4; ++vt) {
        bf16x8 bfr = *(const bf16x8*)(Ebl + vt * 16 * DD + k0);
        acc[vt] = __builtin_amdgcn_mfma_f32_16x16x32_bf16(a, bfr, acc[vt], 0, 0, 0);
      }
    }
  }

  int chunk = blockIdx.y * 2 + wc;   // 0..63
#pragma unroll
  for (int i = 0; i < 4; ++i) {
    float mm = -1e30f;
#pragma unroll
    for (int vt = 0; vt < 4; ++vt) mm = fmaxf(mm, acc[vt][i]);
#pragma unroll
    for (int o = 1; o < 16; o <<= 1) mm = fmaxf(mm, __shfl_xor(mm, o, 64));
    float ss = 0.f;
#pragma unroll
    for (int vt = 0; vt < 4; ++vt) ss += __expf(acc[vt][i] - mm);
#pragma unroll
    for (int o = 1; o < 16; o <<= 1) ss += __shfl_xor(ss, o, 64);
    if ((lane & 15) == 0) {
      int row = row0 + wr * 16 + (lane >> 4) * 4 + i;
      hpart[(row * 64 + chunk) * 2]     = mm;
      hpart[(row * 64 + chunk) * 2 + 1] = ss;
    }
  }
}

// --- fallback f32 head: grid (64 rowgroups of 16, 32 vchunks of 128) -----
__global__ __launch_bounds__(256) void k_head_f32(
    const float* __restrict__ embed, float* __restrict__ ws) {
  int rg = blockIdx.x, vc = blockIdx.y;
  int t = threadIdx.x, vl = t & 63, rs = t >> 6;
  __shared__ float U[16][260];
  int row0 = rg * 16;
  const float* src = (row0 < RR) ? (ws + WS_EMIT + row0 * DD)
                                 : (ws + WS_ZE + (row0 - RR) * DD);
  for (int j = 0; j < 16; j++) U[j][t] = src[j * DD + t];
  __syncthreads();
  float m[4], s[4];
#pragma unroll
  for (int q = 0; q < 4; q++) { m[q] = -1e30f; s[q] = 0.f; }
  for (int it = 0; it < 2; it++) {
    int v = vc * 128 + it * 64 + vl;
    const float4* e4 = (const float4*)(embed + (size_t)v * DD);
    float acc[4] = {0.f, 0.f, 0.f, 0.f};
#pragma unroll 4
    for (int k4 = 0; k4 < 64; k4++) {
      float4 e = e4[k4];
#pragma unroll
      for (int q = 0; q < 4; q++) {
        float4 u = ((const float4*)&U[rs + q*4][0])[k4];
        acc[q] += u.x*e.x + u.y*e.y + u.z*e.z + u.w*e.w;
      }
    }
#pragma unroll
    for (int q = 0; q < 4; q++) {
      float mn = fmaxf(m[q], acc[q]);
      s[q] = s[q] * __expf(m[q] - mn) + __expf(acc[q] - mn);
      m[q] = mn;
    }
  }
#pragma unroll
  for (int o = 32; o > 0; o >>= 1) {
#pragma unroll
    for (int q = 0; q < 4; q++) {
      float mo = __shfl_xor(m[q], o, 64), so = __shfl_xor(s[q], o, 64);
      float mn = fmaxf(m[q], mo);
      s[q] = s[q] * __expf(m[q] - mn) + so * __expf(mo - mn);
      m[q] = mn;
    }
  }
  if (vl == 0) {
#pragma unroll
    for (int q = 0; q < 4; q++) {
      int row = row0 + rs + q*4;
      ws[WS_HPART + (row*32 + vc)*2]     = m[q];
      ws[WS_HPART + (row*32 + vc)*2 + 1] = s[q];
    }
  }
}

// --- ylog[v] = yvec · embed[v] -------------------------------------------
__global__ __launch_bounds__(256) void k_ylog(
    const float* __restrict__ embed, float* __restrict__ ws) {
  __shared__ float y[DD];
  int t = threadIdx.x;
  y[t] = ws[WS_YVEC + t];
  __syncthreads();
  int w = t >> 6, lane = t & 63;
  for (int i = 0; i < 16; i++) {
    int v = blockIdx.x * 64 + i * 4 + w;
    float p = 0.f;
#pragma unroll
    for (int j = 0; j < 4; j++) p += y[lane + 64*j] * embed[v * DD + lane + 64*j];
    p = waveSum(p);
    if (lane == 0) ws[WS_YLOG + v] = p;
  }
}

// --- ylse = logsumexp(ylog) ----------------------------------------------
__global__ __launch_bounds__(256) void k_ylse(float* __restrict__ ws) {
  int t = threadIdx.x;
  float m = -1e30f, s = 0.f;
  for (int v = t; v < VV; v += 256) {
    float lg = ws[WS_YLOG + v];
    float mn = fmaxf(m, lg);
    s = s * __expf(m - mn) + __expf(lg - mn);
    m = mn;
  }
#pragma unroll
  for (int o = 32; o > 0; o >>= 1) {
    float mo = __shfl_xor(m, o, 64), so = __shfl_xor(s, o, 64);
    float mn = fmaxf(m, mo);
    s = s * __expf(m - mn) + so * __expf(mo - mn);
    m = mn;
  }
  __shared__ float rm[4], rv[4];
  int lane = t & 63, w = t >> 6;
  if (lane == 0) { rm[w] = m; rv[w] = s; }
  __syncthreads();
  if (t == 0) {
    float M = fmaxf(fmaxf(rm[0], rm[1]), fmaxf(rm[2], rm[3]));
    float S = rv[0]*__expf(rm[0]-M) + rv[1]*__expf(rm[1]-M) +
              rv[2]*__expf(rm[2]-M) + rv[3]*__expf(rm[3]-M);
    ws[WS_YLSE] = M + logf(S);
  }
}

// --- sel logits: s0,s1,s2 per row ----------------------------------------
__global__ __launch_bounds__(256) void k_sel(
    const float* __restrict__ xks, float* __restrict__ ws) {
  int row = blockIdx.x * 4 + (threadIdx.x >> 6);
  int lane = threadIdx.x & 63;
  const float* xr = ws + WS_XSA0 + row * DD;
  float a0 = 0.f, a1 = 0.f, a2 = 0.f;
#pragma unroll
  for (int j = 0; j < 4; j++) {
    float xv = xr[lane + 64*j];
    a0 += xv * xks[lane + 64*j];
    a1 += xv * xks[DD + lane + 64*j];
    a2 += xv * ws[WS_YK + lane + 64*j];
  }
  a0 = waveSum(a0); a1 = waveSum(a1); a2 = waveSum(a2);
  if (lane == 0) {
    ws[WS_SEL + row*4 + 0] = a0;
    ws[WS_SEL + row*4 + 1] = a1;
    ws[WS_SEL + row*4 + 2] = a2;
  }
}

// --- target logits: dot(cand_row, embed[x]) ------------------------------
__global__ __launch_bounds__(256) void k_tgt(
    const int* __restrict__ x, const float* __restrict__ embed,
    float* __restrict__ ws) {
  int row = blockIdx.x * 4 + (threadIdx.x >> 6);
  int lane = threadIdx.x & 63;
  int r5 = row & (RR - 1);
  const float* vec = (row < RR) ? (ws + WS_EMIT + r5 * DD) : (ws + WS_ZE + r5 * DD);
  int v = x[r5];
  float p = 0.f;
#pragma unroll
  for (int j = 0; j < 4; j++) p += vec[lane + 64*j] * embed[v * DD + lane + 64*j];
  p = waveSum(p);
  if (lane == 0) ws[WS_TGT + row] = p;
}

// --- combine nch per-chunk partials into per-row LSE ---------------------
__global__ __launch_bounds__(256) void k_comb(float* __restrict__ ws, int nch) {
  int row = blockIdx.x * 256 + threadIdx.x;
  const float* hp = ws + WS_HPART + row * nch * 2;
  float M = -1e30f;
  for (int c = 0; c < nch; c++) M = fmaxf(M, hp[c * 2]);
  float S = 0.f;
  for (int c = 0; c < nch; c++) S += hp[c * 2 + 1] * __expf(hp[c * 2] - M);
  ws[WS_LSE + row] = M + logf(S);
}

// --- final: mixture prob at target, sqrt, mean over L, negate ------------
__global__ __launch_bounds__(64) void k_final(
    const int* __restrict__ x, float* __restrict__ ws, float* __restrict__ out) {
  int b = blockIdx.x, l = threadIdx.x, r = b * 64 + l;
  float s0 = ws[WS_SEL + r*4], s1 = ws[WS_SEL + r*4+1], s2 = ws[WS_SEL + r*4+2];
  float mx = fmaxf(s0, fmaxf(s1, s2));
  float den = expf(s0 - mx) + expf(s1 - mx) + 64.f * expf(s2 - mx);
  float lsel = mx + logf(den);
  int xv = x[r];
  float P0 = expf(s0 - lsel + ws[WS_TGT + r]      - ws[WS_LSE + r]);
  float P1 = expf(s1 - lsel + ws[WS_TGT + RR + r] - ws[WS_LSE + RR + r]);
  float Py = expf(s2 - lsel + ws[WS_YLOG + xv]    - ws[WS_YLSE]);
  float cent = sqrtf(P0 + P1 + 64.f * Py);
  float sum = waveSum(cent);
  if (l == 0) out[b] = -(sum * (1.0f / 64.f));
}

extern "C" void kernel_launch(void* const* d_in, const int* in_sizes, int n_in,
                              void* d_out, int out_size, void* d_ws, size_t ws_size,
                              hipStream_t stream) {
  (void)in_sizes; (void)n_in; (void)out_size;
  const int*   x     = (const int*)d_in[0];
  const int*   z     = (const int*)d_in[1];
  const float* embed = (const float*)d_in[2];
  const float* initw = (const float*)d_in[3];
  const float* tw    = (const float*)d_in[4];
  const float* tb    = (const float*)d_in[5];
  const float* cw    = (const float*)d_in[6];
  const float* uw    = (const float*)d_in[7];
  const float* xks   = (const float*)d_in[8];
  const float* xkdw  = (const float*)d_in[9];
  const float* xkdb  = (const float*)d_in[10];
  const float* emiw  = (const float*)d_in[11];
  const float* emib  = (const float*)d_in[12];
  float* ws  = (float*)d_ws;
  float* out = (float*)d_out;

  const bool use_mfma = ws_size >= (size_t)WS_TOTAL_MFMA * sizeof(float);

  hipLaunchKernelGGL(k_norm_rows, dim3(RR + 2), dim3(256), 0, stream, z, embed, initw, ws);
  hipLaunchKernelGGL(k_build_w,   dim3(256),    dim3(256), 0, stream, tw, cw, ws + WS_WCT);
  hipLaunchKernelGGL(k_yk,        dim3(1),      dim3(256), 0, stream, xkdw, xkdb, ws);
  hipLaunchKernelGGL(k_bcast,     dim3(512),    dim3(256), 0, stream, ws);
  hipLaunchKernelGGL(k_rowmat2,   dim3(256),    dim3(256), 0, stream,
                     ws + WS_ZE, uw, tb, ws + WS_ZEU3, 1.0f / 3.0f);
  if (use_mfma) {
    hipLaunchKernelGGL(k_split_e, dim3(1024),   dim3(256), 0, stream, embed,
                       (unsigned short*)(ws + WS_EHI), (unsigned short*)(ws + WS_ELO));
  }
  hipLaunchKernelGGL(k_ylog,      dim3(64),     dim3(256), 0, stream, embed, ws);
  hipLaunchKernelGGL(k_ylse,      dim3(1),      dim3(256), 0, stream, ws);

  // ---- scan: persistent cooperative kernel (fallback: 64 step launches) --
  hipLaunchKernelGGL(k_zero_cnt, dim3(16), dim3(256), 0, stream, (int*)(ws + WS_TOKS));
  {
    float* wsp = ws;
    void* kargs[] = {&wsp};
    hipError_t err = hipLaunchCooperativeKernel(
        reinterpret_cast<void*>(k_scan), dim3(512), dim3(256), kargs, 0, stream);
    if (err != hipSuccess) {
      for (int t = 0; t < 64; t++) {
        const float* xin = ws + ((t & 1) ? WS_XSA1 : WS_XSA0);
        float*       xo  = ws + ((t & 1) ? WS_XSA0 : WS_XSA1);
        hipLaunchKernelGGL(k_step, dim3(32, 8), dim3(256), 0, stream,
                           xin, ws + WS_WCT, ws + WS_ZEU3, xo);
      }
    }
  }

  hipLaunchKernelGGL(k_rowmat2, dim3(256), dim3(256), 0, stream,
                     ws + WS_XSA0, emiw, emib, ws + WS_EMIT, 1.0f);
  hipLaunchKernelGGL(k_sel,     dim3(128), dim3(256), 0, stream, xks, ws);
  hipLaunchKernelGGL(k_tgt,     dim3(256), dim3(256), 0, stream, x, embed, ws);
  if (use_mfma) {
    hipLaunchKernelGGL(k_split_u,   dim3(1024),   dim3(256), 0, stream, ws);
    hipLaunchKernelGGL(k_head_mfma, dim3(32, 32), dim3(256), 0, stream,
                       (const unsigned short*)(ws + WS_UHI),
                       (const unsigned short*)(ws + WS_ULO),
                       (const unsigned short*)(ws + WS_EHI),
                       (const unsigned short*)(ws + WS_ELO),
                       ws + WS_HPART);
    hipLaunchKernelGGL(k_comb,  dim3(4), dim3(256), 0, stream, ws, 64);
  } else {
    hipLaunchKernelGGL(k_head_f32, dim3(64, 32), dim3(256), 0, stream, embed, ws);
    hipLaunchKernelGGL(k_comb,  dim3(4), dim3(256), 0, stream, ws, 32);
  }
  hipLaunchKernelGGL(k_final, dim3(8), dim3(64),  0, stream, x, ws, out);
}

// Round 9
// 474.043 us; speedup vs baseline: 3.5373x; 3.5373x over previous
//
#include <hip/hip_runtime.h>
#include <hip/hip_bf16.h>
#include <math.h>

#define BB 8
#define LL 64
#define DD 256
#define VV 4096
#define RR 512           // BB*LL
#define K3 768

typedef __attribute__((ext_vector_type(4))) float f32x4;
typedef __attribute__((ext_vector_type(8))) short bf16x8;
typedef __attribute__((ext_vector_type(4))) unsigned short u16x4;
typedef unsigned long long u64;

// ---- workspace layout (float offsets) -----------------------------------
#define WS_ZE      0
#define WS_ZEU3    (WS_ZE + RR*DD)           // dead after scan
#define WS_WCT     (WS_ZEU3 + RR*DD)         // dead after scan
#define WS_XSA0    (WS_WCT + DD*K3)          // final scan state
#define WS_XSA1    (WS_XSA0 + RR*DD)         // dead after scan
#define WS_EMIT    (WS_XSA1 + RR*DD)
#define WS_YVEC    (WS_EMIT + RR*DD)
#define WS_X0VEC   (WS_YVEC + DD)
#define WS_YK      (WS_X0VEC + DD)
#define WS_YLOG    (WS_YK + DD)
#define WS_YLSE    (WS_YLOG + VV)
#define WS_SEL     (WS_YLSE + 8)             // region now FREE (finish fused)
// Sync tokens: 64 lines x 128B = 2048 ints in the free SEL region. Nothing
// else ever touches [WS_SEL, WS_EHI): no aliasing with any phase.
#define WS_TOKS    WS_SEL
// Overlays (dead after scan):
#define WS_HPART   WS_WCT                    // 1024*64*2 = 131072 <= 196608
// MFMA tail:
#define WS_EHI     861184
#define WS_ELO     (WS_EHI + VV*DD/2)
#define WS_TOTAL_MFMA (WS_ELO + VV*DD/2)     // 7,639,040 bytes (gate proven R5-R8)

__device__ __forceinline__ float waveSum(float v) {
#pragma unroll
  for (int o = 32; o > 0; o >>= 1) v += __shfl_xor(v, o, 64);
  return v;
}

__device__ __forceinline__ float blockSum256(float v) {
  __shared__ float red[4];
  int lane = threadIdx.x & 63, w = threadIdx.x >> 6;
  v = waveSum(v);
  __syncthreads();
  if (lane == 0) red[w] = v;
  __syncthreads();
  return red[0] + red[1] + red[2] + red[3];
}

__device__ __forceinline__ unsigned short f2bf(float f) {
  unsigned int u = __float_as_uint(f);
  unsigned int r = (u + 0x7fffu + ((u >> 16) & 1u)) >> 16;
  return (unsigned short)r;
}
__device__ __forceinline__ float bf2f(unsigned short h) {
  return __uint_as_float(((unsigned int)h) << 16);
}

union U64F2 { u64 u; float f[2]; };

// --- normalize rows: ze (512), yvec, x0vec -------------------------------
__global__ __launch_bounds__(256) void k_norm_rows(
    const int* __restrict__ z, const float* __restrict__ embed,
    const float* __restrict__ initw, float* __restrict__ ws) {
  int r = blockIdx.x, d = threadIdx.x;
  float a; float* dst;
  if (r < RR) { int tok = z[r]; a = embed[tok * DD + d]; dst = ws + WS_ZE + r * DD; }
  else if (r == RR) { a = embed[d]; dst = ws + WS_YVEC; }
  else { a = initw[d * 16]; dst = ws + WS_X0VEC; }
  float s  = blockSum256(a);
  float sq = blockSum256(a * a);
  float mean = s * (1.0f / DD);
  float var = fmaxf((sq - (float)DD * mean * mean) * (1.0f / (DD - 1)), 0.0f);
  dst[d] = a / (1e-5f + sqrtf(var));
}

// --- build combined transposed weights WcT[c][0:768] = [Tw;TwT;Cw]/3 -----
__global__ __launch_bounds__(256) void k_build_w(
    const float* __restrict__ tw, const float* __restrict__ cw,
    float* __restrict__ wct) {
  int c = blockIdx.x, k = threadIdx.x;
  const float inv3 = 1.0f / 3.0f;
  wct[c * K3 + k]       = tw[k * DD + c] * inv3;  // x[l-1] @ Tw
  wct[c * K3 + 256 + k] = tw[c * DD + k] * inv3;  // x[l+1] @ Tw^T
  wct[c * K3 + 512 + k] = cw[k * DD + c] * inv3;  // x[l]   @ Cw
}

// --- out[r][d] = scale*(in[r]·W[d,:] + bias[d]) ; 2 rows / block ----------
__global__ __launch_bounds__(256) void k_rowmat2(
    const float* __restrict__ in, const float* __restrict__ W,
    const float* __restrict__ bias, float* __restrict__ out, float scale) {
  int r0 = blockIdx.x * 2, d = threadIdx.x;
  __shared__ float u[2][260];
  u[0][d] = in[r0 * DD + d];
  u[1][d] = in[(r0 + 1) * DD + d];
  __syncthreads();
  float a0 = 0.f, a1 = 0.f;
  const float4* w4 = (const float4*)(W + d * DD);
  const float4* u0 = (const float4*)&u[0][0];
  const float4* u1 = (const float4*)&u[1][0];
#pragma unroll 8
  for (int k4 = 0; k4 < 64; k4++) {
    float4 w = w4[k4], x0 = u0[k4], x1 = u1[k4];
    a0 += x0.x*w.x + x0.y*w.y + x0.z*w.z + x0.w*w.w;
    a1 += x1.x*w.x + x1.y*w.y + x1.z*w.z + x1.w*w.w;
  }
  float b = bias[d];
  out[r0 * DD + d]       = (a0 + b) * scale;
  out[(r0 + 1) * DD + d] = (a1 + b) * scale;
}

// --- split embed into bf16 hi/lo -----------------------------------------
__global__ __launch_bounds__(256) void k_split_e(
    const float* __restrict__ e, unsigned short* __restrict__ eh,
    unsigned short* __restrict__ el) {
  int i = (blockIdx.x * 256 + threadIdx.x) * 4;
  float4 v = *(const float4*)(e + i);
  float f[4] = {v.x, v.y, v.z, v.w};
  u16x4 h, l;
#pragma unroll
  for (int j = 0; j < 4; ++j) {
    unsigned short hb = f2bf(f[j]);
    h[j] = hb;
    l[j] = f2bf(f[j] - bf2f(hb));
  }
  *(u16x4*)(eh + i) = h;
  *(u16x4*)(el + i) = l;
}

// --- ylog[v] = yvec · embed[v] -------------------------------------------
__global__ __launch_bounds__(256) void k_ylog(
    const float* __restrict__ embed, float* __restrict__ ws) {
  __shared__ float y[DD];
  int t = threadIdx.x;
  y[t] = ws[WS_YVEC + t];
  __syncthreads();
  int w = t >> 6, lane = t & 63;
  for (int i = 0; i < 16; i++) {
    int v = blockIdx.x * 64 + i * 4 + w;
    float p = 0.f;
#pragma unroll
    for (int j = 0; j < 4; j++) p += y[lane + 64*j] * embed[v * DD + lane + 64*j];
    p = waveSum(p);
    if (lane == 0) ws[WS_YLOG + v] = p;
  }
}

// --- zero the padded sync tokens (each replay): 2048 ints ----------------
__global__ void k_zero_cnt(int* __restrict__ c) {
  c[blockIdx.x * 256 + threadIdx.x] = 0;
}

// --- persistent scan: all 64 steps in one REGULAR launch ------------------
// 512 blocks (<=3/CU capacity at 49KB LDS -> all co-resident), 256 thr.
// Block = 8 rows x 32 cols; W in VGPRs. Data exchange via RELAXED
// agent-scope bypass atomics (R7-proven: no cache-maintenance ops in loop).
// R9: regular launch (coop launch inside graph capture was the suspected
// 1.3ms silent-fallback); single-level token; per-wave poll; step-0 stages
// straight from x0vec.
__global__ __launch_bounds__(256, 2) void k_scan(float* __restrict__ ws) {
  const int bid = blockIdx.x;
  const int rg = bid & 63, cg = bid >> 6;   // siblings (same rg) share XCD
  const int b = rg >> 3, rgl = rg & 7, l0 = rgl * 8;
  const int t = threadIdx.x, lane = t & 63;
  const int cl = t & 7, rs = t >> 3;
  const int c0 = cg * 32 + cl * 4;

  __shared__ float S[10 * 264];
  __shared__ float PAR[32 * 260];
  __shared__ float PAR2[4 * 256];
  __shared__ float ZB[256];

  const float* wct  = ws + WS_WCT;
  const float* zeu3 = ws + WS_ZEU3;
  int* tok = (int*)(ws + WS_TOKS);          // tok[rg] at tok + rg*32

  // ---- W into registers: 4 cols x 3 parts x 8 k = 96 floats (static idx)
  float4 wreg[24];
#pragma unroll
  for (int p = 0; p < 3; ++p)
#pragma unroll
    for (int q = 0; q < 2; ++q)
#pragma unroll
      for (int c4 = 0; c4 < 4; ++c4)
        wreg[(p * 2 + q) * 4 + c4] =
            *(const float4*)&wct[(size_t)(c0 + c4) * K3 + p * 256 + rs * 8 + q * 4];

  { // zeu3 tile (step-invariant)
    int r = t >> 5, c = t & 31;
    ZB[r * 32 + c] = zeu3[(size_t)(b * 64 + l0 + r) * DD + cg * 32 + c];
  }

  const int nb0 = b * 8 + ((rgl + 7) & 7);
  const int nb1 = b * 8 + rgl;
  const int nb2 = b * 8 + ((rgl + 1) & 7);
  const int myl = (lane == 0) ? nb0 : (lane == 1) ? nb1 : nb2;

  for (int st = 0; st < 64; ++st) {
    const float* xin  = ws + ((st & 1) ? WS_XSA1 : WS_XSA0);
    float*       xout = ws + ((st & 1) ? WS_XSA0 : WS_XSA1);

    if (st > 0) {  // every wave polls: lanes 0..2 cover the 3 neighbor lines
      const int tg = st << 3;
      while (true) {
        int v = __hip_atomic_load(tok + myl * 32, __ATOMIC_RELAXED,
                                  __HIP_MEMORY_SCOPE_AGENT);
        if (__all(v >= tg)) break;
        __builtin_amdgcn_s_sleep(1);
      }
    }

    // stage 10 rows x 256 f via bypass u64 loads; step 0 -> x0vec broadcast
#pragma unroll
    for (int it = 0; it < 5; ++it) {
      int idx = it * 256 + t;
      int j = idx >> 7;               // row 0..9
      int kk = (idx & 127) << 1;      // float offset 0..254
      const u64* src = (st == 0)
          ? (const u64*)(ws + WS_X0VEC + kk)
          : (const u64*)(xin + (size_t)(b * 64 + ((l0 + j - 1 + 64) & 63)) * DD + kk);
      u64 v = __hip_atomic_load(src, __ATOMIC_RELAXED, __HIP_MEMORY_SCOPE_AGENT);
      *(u64*)(&S[j * 264 + kk]) = v;
    }
    __syncthreads();

    float acc[8][4];
#pragma unroll
    for (int r = 0; r < 8; ++r)
#pragma unroll
      for (int c4 = 0; c4 < 4; ++c4) acc[r][c4] = 0.f;

#pragma unroll
    for (int p = 0; p < 3; ++p) {
      const int jof = (p == 0) ? 0 : (p == 1) ? 2 : 1;
#pragma unroll
      for (int r = 0; r < 8; ++r) {
#pragma unroll
        for (int q = 0; q < 2; ++q) {
          float4 x = *(const float4*)&S[(r + jof) * 264 + rs * 8 + q * 4];
#pragma unroll
          for (int c4 = 0; c4 < 4; ++c4) {
            float4 w = wreg[(p * 2 + q) * 4 + c4];
            acc[r][c4] += x.x * w.x + x.y * w.y + x.z * w.z + x.w * w.w;
          }
        }
      }
    }

    // partials -> LDS
#pragma unroll
    for (int r = 0; r < 8; ++r) {
      float4 v4 = {acc[r][0], acc[r][1], acc[r][2], acc[r][3]};
      *(float4*)&PAR[rs * 260 + r * 32 + cl * 4] = v4;
    }
    __syncthreads();

    { // reduce 32 -> 4
      int u = t & 63, v = t >> 6;
      float4 s4 = {0.f, 0.f, 0.f, 0.f};
#pragma unroll
      for (int i = 0; i < 8; ++i) {
        float4 p4 = *(const float4*)&PAR[(v * 8 + i) * 260 + u * 4];
        s4.x += p4.x; s4.y += p4.y; s4.z += p4.z; s4.w += p4.w;
      }
      *(float4*)&PAR2[v * 256 + u * 4] = s4;
    }
    __syncthreads();

    if (t < 64) { // reduce 4 -> 1, add zeu3, bypass store (2 x u64)
      int r = t >> 3, c8 = t & 7;
      float4 s4 = {0.f, 0.f, 0.f, 0.f};
#pragma unroll
      for (int v = 0; v < 4; ++v) {
        float4 p4 = *(const float4*)&PAR2[v * 256 + t * 4];
        s4.x += p4.x; s4.y += p4.y; s4.z += p4.z; s4.w += p4.w;
      }
      float4 zb = *(const float4*)&ZB[r * 32 + c8 * 4];
      s4.x += zb.x; s4.y += zb.y; s4.z += zb.z; s4.w += zb.w;
      size_t off = (size_t)(b * 64 + l0 + r) * DD + cg * 32 + c8 * 4;
      U64F2 lo, hi;
      lo.f[0] = s4.x; lo.f[1] = s4.y;
      hi.f[0] = s4.z; hi.f[1] = s4.w;
      __hip_atomic_store((u64*)(xout + off),     lo.u, __ATOMIC_RELAXED, __HIP_MEMORY_SCOPE_AGENT);
      __hip_atomic_store((u64*)(xout + off + 2), hi.u, __ATOMIC_RELAXED, __HIP_MEMORY_SCOPE_AGENT);
    }

    // syncthreads drains vmcnt(0): bypass stores globally visible first.
    __syncthreads();
    if (t == 0)
      __hip_atomic_fetch_add(tok + nb1 * 32, 1, __ATOMIC_RELAXED,
                             __HIP_MEMORY_SCOPE_AGENT);
  }
}

// --- head GEMM via MFMA, split-precision bf16, in-LDS U split ------------
// grid (32 rowgroups of 32, 32 vchunks of 128), 256 thr = 4 waves.
__global__ __launch_bounds__(256) void k_head_mfma(
    const float* __restrict__ uemit, const float* __restrict__ uze,
    const unsigned short* __restrict__ eh, const unsigned short* __restrict__ el,
    float* __restrict__ hpart) {
  int row0 = blockIdx.x * 32;
  int v0 = blockIdx.y * 128;
  int t = threadIdx.x, lane = t & 63, w = t >> 6;
  int wr = w >> 1, wc = w & 1;
  __shared__ unsigned short UH[32 * 264];
  __shared__ unsigned short UL[32 * 264];
  const float* src = (row0 < RR) ? (uemit + (size_t)row0 * DD)
                                 : (uze + (size_t)(row0 - RR) * DD);
#pragma unroll
  for (int it = 0; it < 4; ++it) {
    int r = it * 8 + (t >> 5);
    int c8 = (t & 31) * 8;
    float4 a = *(const float4*)(src + (size_t)r * DD + c8);
    float4 b2 = *(const float4*)(src + (size_t)r * DD + c8 + 4);
    float fa[8] = {a.x, a.y, a.z, a.w, b2.x, b2.y, b2.z, b2.w};
    u16x4 h0, l0, h1, l1;
#pragma unroll
    for (int j = 0; j < 4; ++j) {
      unsigned short hb = f2bf(fa[j]);
      h0[j] = hb; l0[j] = f2bf(fa[j] - bf2f(hb));
      unsigned short hb1 = f2bf(fa[4 + j]);
      h1[j] = hb1; l1[j] = f2bf(fa[4 + j] - bf2f(hb1));
    }
    *(u16x4*)(&UH[r * 264 + c8])     = h0;
    *(u16x4*)(&UH[r * 264 + c8 + 4]) = h1;
    *(u16x4*)(&UL[r * 264 + c8])     = l0;
    *(u16x4*)(&UL[r * 264 + c8 + 4]) = l1;
  }
  __syncthreads();

  f32x4 acc[4];
#pragma unroll
  for (int q = 0; q < 4; ++q) acc[q] = (f32x4){0.f, 0.f, 0.f, 0.f};

  int arow = wr * 16 + (lane & 15);
  int kof = 8 * (lane >> 4);
  const unsigned short* Ah = &UH[arow * 264 + kof];
  const unsigned short* Al = &UL[arow * 264 + kof];
  int vbase = v0 + wc * 64 + (lane & 15);

#pragma unroll
  for (int p = 0; p < 3; ++p) {
    const unsigned short* Ab = (p == 2) ? Al : Ah;
    const unsigned short* Ebl = ((p == 1) ? el : eh) + (size_t)vbase * DD + kof;
#pragma unroll
    for (int ks = 0; ks < 8; ++ks) {
      int k0 = ks * 32;
      bf16x8 a = *(const bf16x8*)(Ab + k0);
#pragma unroll
      for (int vt = 0; vt < 4; ++vt) {
        bf16x8 bfr = *(const bf16x8*)(Ebl + vt * 16 * DD + k0);
        acc[vt] = __builtin_amdgcn_mfma_f32_16x16x32_bf16(a, bfr, acc[vt], 0, 0, 0);
      }
    }
  }

  int chunk = blockIdx.y * 2 + wc;   // 0..63
#pragma unroll
  for (int i = 0; i < 4; ++i) {
    float mm = -1e30f;
#pragma unroll
    for (int vt = 0; vt < 4; ++vt) mm = fmaxf(mm, acc[vt][i]);
#pragma unroll
    for (int o = 1; o < 16; o <<= 1) mm = fmaxf(mm, __shfl_xor(mm, o, 64));
    float ss = 0.f;
#pragma unroll
    for (int vt = 0; vt < 4; ++vt) ss += __expf(acc[vt][i] - mm);
#pragma unroll
    for (int o = 1; o < 16; o <<= 1) ss += __shfl_xor(ss, o, 64);
    if ((lane & 15) == 0) {
      int row = row0 + wr * 16 + (lane >> 4) * 4 + i;
      hpart[(row * 64 + chunk) * 2]     = mm;
      hpart[(row * 64 + chunk) * 2 + 1] = ss;
    }
  }
}

// --- finish: yk + ylse + sel + tgt + comb + final, fused; grid(8) --------
__global__ __launch_bounds__(256) void k_finish(
    const int* __restrict__ x, const float* __restrict__ embed,
    const float* __restrict__ xks, const float* __restrict__ xkdw,
    const float* __restrict__ xkdb, float* __restrict__ ws,
    float* __restrict__ out) {
  int b = blockIdx.x, t = threadIdx.x, lane = t & 63, w = t >> 6;
  __shared__ float YK[DD];
  __shared__ float rm[4], rv[4];
  __shared__ float ylse_s;
  __shared__ float sel0[64], sel1[64], sel2[64], tg0[64], tg1[64];
  __shared__ float ls0s[64], ls1s[64];

  { // yk[d] = xkdb[d] + yvec . xkdw[d,:]
    float acc = xkdb[t];
    const float4* yv4 = (const float4*)(ws + WS_YVEC);
    const float4* w4 = (const float4*)(xkdw + (size_t)t * DD);
    float a = 0.f;
#pragma unroll 8
    for (int k4 = 0; k4 < 64; ++k4) {
      float4 yv = yv4[k4], wv = w4[k4];
      a += yv.x*wv.x + yv.y*wv.y + yv.z*wv.z + yv.w*wv.w;
    }
    YK[t] = acc + a;
  }
  { // ylse (redundant per block, cheap)
    float m = -1e30f, s = 0.f;
    for (int v = t; v < VV; v += 256) {
      float lg = ws[WS_YLOG + v];
      float mn = fmaxf(m, lg);
      s = s * __expf(m - mn) + __expf(lg - mn);
      m = mn;
    }
#pragma unroll
    for (int o = 32; o > 0; o >>= 1) {
      float mo = __shfl_xor(m, o, 64), so = __shfl_xor(s, o, 64);
      float mn = fmaxf(m, mo);
      s = s * __expf(m - mn) + so * __expf(mo - mn);
      m = mn;
    }
    if (lane == 0) { rm[w] = m; rv[w] = s; }
  }
  __syncthreads();
  if (t == 0) {
    float M = fmaxf(fmaxf(rm[0], rm[1]), fmaxf(rm[2], rm[3]));
    float S = rv[0]*__expf(rm[0]-M) + rv[1]*__expf(rm[1]-M) +
              rv[2]*__expf(rm[2]-M) + rv[3]*__expf(rm[3]-M);
    ylse_s = M + logf(S);
  }

  const float* hp = ws + WS_HPART;
  for (int i = 0; i < 16; ++i) {
    int l = w * 16 + i, r = b * 64 + l;
    float4 xs = *(const float4*)&ws[WS_XSA0 + (size_t)r * DD + lane * 4];
    float4 k0 = *(const float4*)&xks[lane * 4];
    float4 k1 = *(const float4*)&xks[DD + lane * 4];
    float4 yk4 = *(const float4*)&YK[lane * 4];
    float s0 = waveSum(xs.x*k0.x + xs.y*k0.y + xs.z*k0.z + xs.w*k0.w);
    float s1 = waveSum(xs.x*k1.x + xs.y*k1.y + xs.z*k1.z + xs.w*k1.w);
    float s2 = waveSum(xs.x*yk4.x + xs.y*yk4.y + xs.z*yk4.z + xs.w*yk4.w);
    int xv = x[r];
    float4 e4 = *(const float4*)&embed[(size_t)xv * DD + lane * 4];
    float4 em = *(const float4*)&ws[WS_EMIT + (size_t)r * DD + lane * 4];
    float4 zr = *(const float4*)&ws[WS_ZE + (size_t)r * DD + lane * 4];
    float t0 = waveSum(em.x*e4.x + em.y*e4.y + em.z*e4.z + em.w*e4.w);
    float t1 = waveSum(zr.x*e4.x + zr.y*e4.y + zr.z*e4.z + zr.w*e4.w);
    // comb: 64 chunks, lane c holds chunk c; butterfly online-LSE merge
    float m0 = hp[((size_t)r * 64 + lane) * 2];
    float q0 = hp[((size_t)r * 64 + lane) * 2 + 1];
    float m1 = hp[((size_t)(RR + r) * 64 + lane) * 2];
    float q1 = hp[((size_t)(RR + r) * 64 + lane) * 2 + 1];
#pragma unroll
    for (int o = 32; o > 0; o >>= 1) {
      float mo = __shfl_xor(m0, o, 64), so = __shfl_xor(q0, o, 64);
      float mn = fmaxf(m0, mo);
      q0 = q0 * __expf(m0 - mn) + so * __expf(mo - mn);
      m0 = mn;
      mo = __shfl_xor(m1, o, 64); so = __shfl_xor(q1, o, 64);
      mn = fmaxf(m1, mo);
      q1 = q1 * __expf(m1 - mn) + so * __expf(mo - mn);
      m1 = mn;
    }
    if (lane == 0) {
      sel0[l] = s0; sel1[l] = s1; sel2[l] = s2;
      tg0[l] = t0; tg1[l] = t1;
      ls0s[l] = m0 + logf(q0);
      ls1s[l] = m1 + logf(q1);
    }
  }
  __syncthreads();
  if (w == 0) {
    int l = lane, r = b * 64 + l;
    float s0 = sel0[l], s1 = sel1[l], s2 = sel2[l];
    float mx = fmaxf(s0, fmaxf(s1, s2));
    float den = expf(s0 - mx) + expf(s1 - mx) + 64.f * expf(s2 - mx);
    float lsel = mx + logf(den);
    int xv = x[r];
    float P0 = expf(s0 - lsel + tg0[l] - ls0s[l]);
    float P1 = expf(s1 - lsel + tg1[l] - ls1s[l]);
    float Py = expf(s2 - lsel + ws[WS_YLOG + xv] - ylse_s);
    float cent = sqrtf(P0 + P1 + 64.f * Py);
    float sum = waveSum(cent);
    if (lane == 0) out[b] = -(sum * (1.0f / 64.f));
  }
}

extern "C" void kernel_launch(void* const* d_in, const int* in_sizes, int n_in,
                              void* d_out, int out_size, void* d_ws, size_t ws_size,
                              hipStream_t stream) {
  (void)in_sizes; (void)n_in; (void)out_size; (void)ws_size;
  const int*   x     = (const int*)d_in[0];
  const int*   z     = (const int*)d_in[1];
  const float* embed = (const float*)d_in[2];
  const float* initw = (const float*)d_in[3];
  const float* tw    = (const float*)d_in[4];
  const float* tb    = (const float*)d_in[5];
  const float* cw    = (const float*)d_in[6];
  const float* uw    = (const float*)d_in[7];
  const float* xks   = (const float*)d_in[8];
  const float* xkdw  = (const float*)d_in[9];
  const float* xkdb  = (const float*)d_in[10];
  const float* emiw  = (const float*)d_in[11];
  const float* emib  = (const float*)d_in[12];
  float* ws  = (float*)d_ws;
  float* out = (float*)d_out;

  hipLaunchKernelGGL(k_norm_rows, dim3(RR + 2), dim3(256), 0, stream, z, embed, initw, ws);
  hipLaunchKernelGGL(k_build_w,   dim3(256),    dim3(256), 0, stream, tw, cw, ws + WS_WCT);
  hipLaunchKernelGGL(k_rowmat2,   dim3(256),    dim3(256), 0, stream,
                     ws + WS_ZE, uw, tb, ws + WS_ZEU3, 1.0f / 3.0f);
  hipLaunchKernelGGL(k_split_e,   dim3(1024),   dim3(256), 0, stream, embed,
                     (unsigned short*)(ws + WS_EHI), (unsigned short*)(ws + WS_ELO));
  hipLaunchKernelGGL(k_ylog,      dim3(64),     dim3(256), 0, stream, embed, ws);

  // ---- scan: persistent kernel, REGULAR launch (graph-capture-safe) -----
  hipLaunchKernelGGL(k_zero_cnt, dim3(8), dim3(256), 0, stream, (int*)(ws + WS_TOKS));
  hipLaunchKernelGGL(k_scan, dim3(512), dim3(256), 0, stream, ws);

  hipLaunchKernelGGL(k_rowmat2, dim3(256), dim3(256), 0, stream,
                     ws + WS_XSA0, emiw, emib, ws + WS_EMIT, 1.0f);
  hipLaunchKernelGGL(k_head_mfma, dim3(32, 32), dim3(256), 0, stream,
                     ws + WS_EMIT, ws + WS_ZE,
                     (const unsigned short*)(ws + WS_EHI),
                     (const unsigned short*)(ws + WS_ELO),
                     ws + WS_HPART);
  hipLaunchKernelGGL(k_finish, dim3(8), dim3(256), 0, stream,
                     x, embed, xks, xkdw, xkdb, ws, out);
}

// Round 11
// 367.988 us; speedup vs baseline: 4.5568x; 1.2882x over previous
//
#include <hip/hip_runtime.h>
#include <hip/hip_bf16.h>
#include <math.h>

#define BB 8
#define LL 64
#define DD 256
#define VV 4096
#define RR 512           // BB*LL
#define K3 768

typedef __attribute__((ext_vector_type(4))) float f32x4;
typedef __attribute__((ext_vector_type(8))) short bf16x8;
typedef __attribute__((ext_vector_type(4))) unsigned short u16x4;
typedef unsigned long long u64;

// ---- workspace layout (float offsets) -----------------------------------
#define WS_ZE      0
#define WS_ZEU3    (WS_ZE + RR*DD)           // z; then M5 parts 3,4
#define WS_WCT     (WS_ZEU3 + RR*DD)         // M5 parts 0,1,2 (3*65536=196608)
#define WS_XSA0    (WS_WCT + DD*K3)          // scan ping (twT/cwT pre-scan)
#define WS_XSA1    (WS_XSA0 + RR*DD)         // scan pong (holds z2 at scan start)
#define WS_EMIT    (WS_XSA1 + RR*DD)
#define WS_YVEC    (WS_EMIT + RR*DD)
#define WS_X0VEC   (WS_YVEC + DD)
#define WS_YK      (WS_X0VEC + DD)
#define WS_YLOG    (WS_YK + DD)
#define WS_YLSE    (WS_YLOG + VV)
#define WS_SEL     (WS_YLSE + 8)
#define WS_TOKS    WS_SEL                    // 64 lines x 32 ints = 2048 ints
#define WS_HPART   WS_WCT                    // head partials overlay (post-scan)
// temp (pre-scan only), inside XSA0:
#define WS_TWT     WS_XSA0                   // 65536 floats  (tw^T)
#define WS_CWT     (WS_XSA0 + 65536)         // 65536 floats  (cw^T)
// MFMA tail:
#define WS_EHI     861184
#define WS_ELO     (WS_EHI + VV*DD/2)

__device__ __forceinline__ float waveSum(float v) {
#pragma unroll
  for (int o = 32; o > 0; o >>= 1) v += __shfl_xor(v, o, 64);
  return v;
}

__device__ __forceinline__ float blockSum256(float v) {
  __shared__ float red[4];
  int lane = threadIdx.x & 63, w = threadIdx.x >> 6;
  v = waveSum(v);
  __syncthreads();
  if (lane == 0) red[w] = v;
  __syncthreads();
  return red[0] + red[1] + red[2] + red[3];
}

__device__ __forceinline__ unsigned short f2bf(float f) {
  unsigned int u = __float_as_uint(f);
  unsigned int r = (u + 0x7fffu + ((u >> 16) & 1u)) >> 16;
  return (unsigned short)r;
}
__device__ __forceinline__ float bf2f(unsigned short h) {
  return __uint_as_float(((unsigned int)h) << 16);
}

union U64F2 { u64 u; float f[2]; };

// --- normalize rows: ze (512), yvec, x0vec -------------------------------
__global__ __launch_bounds__(256) void k_norm_rows(
    const int* __restrict__ z, const float* __restrict__ embed,
    const float* __restrict__ initw, float* __restrict__ ws) {
  int r = blockIdx.x, d = threadIdx.x;
  float a; float* dst;
  if (r < RR) { int tok = z[r]; a = embed[tok * DD + d]; dst = ws + WS_ZE + r * DD; }
  else if (r == RR) { a = embed[d]; dst = ws + WS_YVEC; }
  else { a = initw[d * 16]; dst = ws + WS_X0VEC; }
  float s  = blockSum256(a);
  float sq = blockSum256(a * a);
  float mean = s * (1.0f / DD);
  float var = fmaxf((sq - (float)DD * mean * mean) * (1.0f / (DD - 1)), 0.0f);
  dst[d] = a / (1e-5f + sqrtf(var));
}

// --- out[r][d] = scale*(in[r]·W[d,:] + bias[d]) ; 2 rows / block ----------
__global__ __launch_bounds__(256) void k_rowmat2(
    const float* __restrict__ in, const float* __restrict__ W,
    const float* __restrict__ bias, float* __restrict__ out, float scale) {
  int r0 = blockIdx.x * 2, d = threadIdx.x;
  __shared__ float u[2][260];
  u[0][d] = in[r0 * DD + d];
  u[1][d] = in[(r0 + 1) * DD + d];
  __syncthreads();
  float a0 = 0.f, a1 = 0.f;
  const float4* w4 = (const float4*)(W + d * DD);
  const float4* u0 = (const float4*)&u[0][0];
  const float4* u1 = (const float4*)&u[1][0];
#pragma unroll 8
  for (int k4 = 0; k4 < 64; k4++) {
    float4 w = w4[k4], x0 = u0[k4], x1 = u1[k4];
    a0 += x0.x*w.x + x0.y*w.y + x0.z*w.z + x0.w*w.w;
    a1 += x1.x*w.x + x1.y*w.y + x1.z*w.z + x1.w*w.w;
  }
  float b = bias[d];
  out[r0 * DD + d]       = (a0 + b) * scale;
  out[(r0 + 1) * DD + d] = (a1 + b) * scale;
}

// --- transposes: twT, cwT (pre-scan temp in XSA0) ------------------------
__global__ __launch_bounds__(256) void k_tr2(
    const float* __restrict__ tw, const float* __restrict__ cw,
    float* __restrict__ ws) {
  int c = blockIdx.x, k = threadIdx.x;
  ws[WS_TWT + c * DD + k] = tw[k * DD + c];
  ws[WS_CWT + c * DD + k] = cw[k * DD + c];
}

// --- z2[l] = z[l-1]@A + z[l+1]@B + z[l]@C + z[l]  (A=tw/3,B=twT/3,C=cw/3)
// R10 BUG FIX: z is position-dependent, so the composed affine term mixes
// NEIGHBOR z rows (z[l-1]A + z[l+1]B + z[l]C), not z[l](A+B+C).
// 2 rows/block; per-thread col c: A-col = twT row c, B-col = tw row c,
// C-col = cwT row c (all contiguous float4).
__global__ __launch_bounds__(256) void k_zmat2(
    const float* __restrict__ tw, float* __restrict__ ws) {
  int r0 = blockIdx.x * 2, c = threadIdx.x;
  int b = r0 >> 6, l = r0 & 63;
  const float* zb = ws + WS_ZEU3 + (size_t)b * 64 * DD;
  float* zout = ws + WS_XSA1;
  __shared__ float zs[4][260];   // rows l-1, l, l+1, l+2 (wrap mod 64)
#pragma unroll
  for (int j = 0; j < 4; ++j) {
    int ll = (l + j - 1 + 64) & 63;
    zs[j][c] = zb[ll * DD + c];
  }
  __syncthreads();
  const float4* wA = (const float4*)(ws + WS_TWT + (size_t)c * DD);
  const float4* wB = (const float4*)(tw + (size_t)c * DD);
  const float4* wC = (const float4*)(ws + WS_CWT + (size_t)c * DD);
  const float4* zm0 = (const float4*)&zs[0][0];
  const float4* z00 = (const float4*)&zs[1][0];
  const float4* zp0 = (const float4*)&zs[2][0];
  const float4* zp1 = (const float4*)&zs[3][0];
  float a0 = 0.f, a1 = 0.f;
#pragma unroll 8
  for (int k4 = 0; k4 < 64; ++k4) {
    float4 A4 = wA[k4], B4 = wB[k4], C4 = wC[k4];
    float4 m0 = zm0[k4], z0 = z00[k4], p0 = zp0[k4], p1 = zp1[k4];
    a0 += m0.x*A4.x + m0.y*A4.y + m0.z*A4.z + m0.w*A4.w
        + p0.x*B4.x + p0.y*B4.y + p0.z*B4.z + p0.w*B4.w
        + z0.x*C4.x + z0.y*C4.y + z0.z*C4.z + z0.w*C4.w;
    a1 += z0.x*A4.x + z0.y*A4.y + z0.z*A4.z + z0.w*A4.w
        + p1.x*B4.x + p1.y*B4.y + p1.z*B4.z + p1.w*B4.w
        + p0.x*C4.x + p0.y*C4.y + p0.z*C4.z + p0.w*C4.w;
  }
  const float inv3 = 1.0f / 3.0f;
  zout[(size_t)r0 * DD + c]       = a0 * inv3 + zs[1][c];
  zout[(size_t)(r0 + 1) * DD + c] = a1 * inv3 + zs[2][c];
}

// --- build the 5 squared-step matrices M[p][k][c], p: o=p-2 --------------
// M-2=A2, M-1=CA+AC, M0=BA+AB+C2, M+1=CB+BC, M+2=B2  (A=tw/3,B=twT/3,C=cw/3)
__global__ __launch_bounds__(256) void k_build_w2(
    const float* __restrict__ tw, const float* __restrict__ cw,
    float* __restrict__ ws) {
  int k = blockIdx.x, c = threadIdx.x;
  const float* twT = ws + WS_TWT;
  __shared__ float rA[DD], rB[DD], rC[DD];
  const float inv9 = 1.0f / 9.0f;
  rA[c] = tw[k * DD + c] * inv9;
  rB[c] = twT[k * DD + c] * inv9;
  rC[c] = cw[k * DD + c] * inv9;
  __syncthreads();
  float a2 = 0.f, m1 = 0.f, m0 = 0.f, m3 = 0.f, b2 = 0.f;
#pragma unroll 4
  for (int j = 0; j < DD; ++j) {
    float Aj = tw[j * DD + c];
    float Bj = twT[j * DD + c];
    float Cj = cw[j * DD + c];
    float ra = rA[j], rb = rB[j], rc = rC[j];
    a2 += ra * Aj;
    m1 += rc * Aj + ra * Cj;
    m0 += rb * Aj + ra * Bj + rc * Cj;
    m3 += rc * Bj + rb * Cj;
    b2 += rb * Bj;
  }
  float* p0 = ws + WS_WCT;
  float* p3 = ws + WS_ZEU3;
  p0[k * DD + c]               = a2;
  p0[65536 + k * DD + c]       = m1;
  p0[2 * 65536 + k * DD + c]   = m0;
  p3[k * DD + c]               = m3;
  p3[65536 + k * DD + c]       = b2;
}

// --- split embed into bf16 hi/lo -----------------------------------------
__global__ __launch_bounds__(256) void k_split_e(
    const float* __restrict__ e, unsigned short* __restrict__ eh,
    unsigned short* __restrict__ el) {
  int i = (blockIdx.x * 256 + threadIdx.x) * 4;
  float4 v = *(const float4*)(e + i);
  float f[4] = {v.x, v.y, v.z, v.w};
  u16x4 h, l;
#pragma unroll
  for (int j = 0; j < 4; ++j) {
    unsigned short hb = f2bf(f[j]);
    h[j] = hb;
    l[j] = f2bf(f[j] - bf2f(hb));
  }
  *(u16x4*)(eh + i) = h;
  *(u16x4*)(el + i) = l;
}

// --- ylog[v] = yvec · embed[v] -------------------------------------------
__global__ __launch_bounds__(256) void k_ylog(
    const float* __restrict__ embed, float* __restrict__ ws) {
  __shared__ float y[DD];
  int t = threadIdx.x;
  y[t] = ws[WS_YVEC + t];
  __syncthreads();
  int w = t >> 6, lane = t & 63;
  for (int i = 0; i < 16; i++) {
    int v = blockIdx.x * 64 + i * 4 + w;
    float p = 0.f;
#pragma unroll
    for (int j = 0; j < 4; j++) p += y[lane + 64*j] * embed[v * DD + lane + 64*j];
    p = waveSum(p);
    if (lane == 0) ws[WS_YLOG + v] = p;
  }
}

// --- zero the padded sync tokens (each replay): 2048 ints ----------------
__global__ void k_zero_cnt(int* __restrict__ c) {
  c[blockIdx.x * 256 + threadIdx.x] = 0;
}

// --- persistent scan: 32 SQUARED steps, regular launch -------------------
// 512 blocks (2/CU), 256 thr; block = 8 rows x 32 cols; 5-part W (K=1280)
// in VGPRs (40 f32x4). Halo +-2 -> stage 12 rows. Sync: R9 token scheme.
__global__ __launch_bounds__(256, 2) void k_scan(float* __restrict__ ws) {
  const int bid = blockIdx.x;
  const int rg = bid & 63, cg = bid >> 6;
  const int b = rg >> 3, rgl = rg & 7, l0 = rgl * 8;
  const int t = threadIdx.x, lane = t & 63;
  const int cl = t & 7, rs = t >> 3;
  const int c0 = cg * 32 + cl * 4;

  __shared__ float S[12 * 264];
  __shared__ float PAR[32 * 260];
  __shared__ float PAR2[4 * 256];
  __shared__ float ZB[256];

  int* tok = (int*)(ws + WS_TOKS);

  const float* Wp[5] = {ws + WS_WCT, ws + WS_WCT + 65536, ws + WS_WCT + 2*65536,
                        ws + WS_ZEU3, ws + WS_ZEU3 + 65536};
  f32x4 wreg[40];
#pragma unroll
  for (int p = 0; p < 5; ++p)
#pragma unroll
    for (int q = 0; q < 2; ++q)
#pragma unroll
      for (int kk = 0; kk < 4; ++kk)
        wreg[p * 8 + q * 4 + kk] =
            *(const f32x4*)&Wp[p][(size_t)(rs * 8 + q * 4 + kk) * DD + c0];

  { // z2 tile from XSA1 (own tile only; written pre-scan by k_zmat2)
    int r = t >> 5, c = t & 31;
    ZB[r * 32 + c] = ws[WS_XSA1 + (size_t)(b * 64 + l0 + r) * DD + cg * 32 + c];
  }

  const int nb0 = b * 8 + ((rgl + 7) & 7);
  const int nb1 = b * 8 + rgl;
  const int nb2 = b * 8 + ((rgl + 1) & 7);
  const int myl = (lane == 0) ? nb0 : (lane == 1) ? nb1 : nb2;

  for (int st = 0; st < 32; ++st) {
    const float* xin  = ws + ((st & 1) ? WS_XSA1 : WS_XSA0);
    float*       xout = ws + ((st & 1) ? WS_XSA0 : WS_XSA1);

    if (st > 0) {
      const int tg = st << 3;
      while (true) {
        int v = __hip_atomic_load(tok + myl * 32, __ATOMIC_RELAXED,
                                  __HIP_MEMORY_SCOPE_AGENT);
        if (__all(v >= tg)) break;
        __builtin_amdgcn_s_sleep(1);
      }
    }

    // stage 12 rows x 256 f (1536 u64, 6/thread); st=0 -> x0vec broadcast
#pragma unroll
    for (int it = 0; it < 6; ++it) {
      int idx = it * 256 + t;
      int j = idx >> 7;
      int kk = (idx & 127) << 1;
      const u64* src = (st == 0)
          ? (const u64*)(ws + WS_X0VEC + kk)
          : (const u64*)(xin + (size_t)(b * 64 + ((l0 + j - 2 + 64) & 63)) * DD + kk);
      u64 v = __hip_atomic_load(src, __ATOMIC_RELAXED, __HIP_MEMORY_SCOPE_AGENT);
      *(u64*)(&S[j * 264 + kk]) = v;
    }
    __syncthreads();

    f32x4 acc[8];
#pragma unroll
    for (int r = 0; r < 8; ++r) acc[r] = (f32x4){0.f, 0.f, 0.f, 0.f};

#pragma unroll
    for (int p = 0; p < 5; ++p) {
#pragma unroll
      for (int r = 0; r < 8; ++r) {
        int j = r + p;                // S[j] = x[l0 + j - 2]
#pragma unroll
        for (int q = 0; q < 2; ++q) {
          f32x4 xv = *(const f32x4*)&S[j * 264 + rs * 8 + q * 4];
          acc[r] += xv.x * wreg[p * 8 + q * 4 + 0];
          acc[r] += xv.y * wreg[p * 8 + q * 4 + 1];
          acc[r] += xv.z * wreg[p * 8 + q * 4 + 2];
          acc[r] += xv.w * wreg[p * 8 + q * 4 + 3];
        }
      }
    }

#pragma unroll
    for (int r = 0; r < 8; ++r)
      *(f32x4*)&PAR[rs * 260 + r * 32 + cl * 4] = acc[r];
    __syncthreads();

    {
      int u = t & 63, v = t >> 6;
      f32x4 s4 = (f32x4){0.f, 0.f, 0.f, 0.f};
#pragma unroll
      for (int i = 0; i < 8; ++i)
        s4 += *(const f32x4*)&PAR[(v * 8 + i) * 260 + u * 4];
      *(f32x4*)&PAR2[v * 256 + u * 4] = s4;
    }
    __syncthreads();

    if (t < 64) {
      int r = t >> 3, c8 = t & 7;
      f32x4 s4 = (f32x4){0.f, 0.f, 0.f, 0.f};
#pragma unroll
      for (int v = 0; v < 4; ++v)
        s4 += *(const f32x4*)&PAR2[v * 256 + t * 4];
      f32x4 zb = *(const f32x4*)&ZB[r * 32 + c8 * 4];
      s4 += zb;
      size_t off = (size_t)(b * 64 + l0 + r) * DD + cg * 32 + c8 * 4;
      U64F2 lo, hi;
      lo.f[0] = s4.x; lo.f[1] = s4.y;
      hi.f[0] = s4.z; hi.f[1] = s4.w;
      __hip_atomic_store((u64*)(xout + off),     lo.u, __ATOMIC_RELAXED, __HIP_MEMORY_SCOPE_AGENT);
      __hip_atomic_store((u64*)(xout + off + 2), hi.u, __ATOMIC_RELAXED, __HIP_MEMORY_SCOPE_AGENT);
    }

    __syncthreads();   // drains vmcnt(0): bypass stores visible first
    if (t == 0)
      __hip_atomic_fetch_add(tok + nb1 * 32, 1, __ATOMIC_RELAXED,
                             __HIP_MEMORY_SCOPE_AGENT);
  }
}

// --- head GEMM via MFMA, split-precision bf16, in-LDS U split ------------
__global__ __launch_bounds__(256) void k_head_mfma(
    const float* __restrict__ uemit, const float* __restrict__ uze,
    const unsigned short* __restrict__ eh, const unsigned short* __restrict__ el,
    float* __restrict__ hpart) {
  int row0 = blockIdx.x * 32;
  int v0 = blockIdx.y * 128;
  int t = threadIdx.x, lane = t & 63, w = t >> 6;
  int wr = w >> 1, wc = w & 1;
  __shared__ unsigned short UH[32 * 264];
  __shared__ unsigned short UL[32 * 264];
  const float* src = (row0 < RR) ? (uemit + (size_t)row0 * DD)
                                 : (uze + (size_t)(row0 - RR) * DD);
#pragma unroll
  for (int it = 0; it < 4; ++it) {
    int r = it * 8 + (t >> 5);
    int c8 = (t & 31) * 8;
    float4 a = *(const float4*)(src + (size_t)r * DD + c8);
    float4 b2 = *(const float4*)(src + (size_t)r * DD + c8 + 4);
    float fa[8] = {a.x, a.y, a.z, a.w, b2.x, b2.y, b2.z, b2.w};
    u16x4 h0, l0v, h1, l1;
#pragma unroll
    for (int j = 0; j < 4; ++j) {
      unsigned short hb = f2bf(fa[j]);
      h0[j] = hb; l0v[j] = f2bf(fa[j] - bf2f(hb));
      unsigned short hb1 = f2bf(fa[4 + j]);
      h1[j] = hb1; l1[j] = f2bf(fa[4 + j] - bf2f(hb1));
    }
    *(u16x4*)(&UH[r * 264 + c8])     = h0;
    *(u16x4*)(&UH[r * 264 + c8 + 4]) = h1;
    *(u16x4*)(&UL[r * 264 + c8])     = l0v;
    *(u16x4*)(&UL[r * 264 + c8 + 4]) = l1;
  }
  __syncthreads();

  f32x4 acc[4];
#pragma unroll
  for (int q = 0; q < 4; ++q) acc[q] = (f32x4){0.f, 0.f, 0.f, 0.f};

  int arow = wr * 16 + (lane & 15);
  int kof = 8 * (lane >> 4);
  const unsigned short* Ah = &UH[arow * 264 + kof];
  const unsigned short* Al = &UL[arow * 264 + kof];
  int vbase = v0 + wc * 64 + (lane & 15);

#pragma unroll
  for (int p = 0; p < 3; ++p) {
    const unsigned short* Ab = (p == 2) ? Al : Ah;
    const unsigned short* Ebl = ((p == 1) ? el : eh) + (size_t)vbase * DD + kof;
#pragma unroll
    for (int ks = 0; ks < 8; ++ks) {
      int k0 = ks * 32;
      bf16x8 a = *(const bf16x8*)(Ab + k0);
#pragma unroll
      for (int vt = 0; vt < 4; ++vt) {
        bf16x8 bfr = *(const bf16x8*)(Ebl + vt * 16 * DD + k0);
        acc[vt] = __builtin_amdgcn_mfma_f32_16x16x32_bf16(a, bfr, acc[vt], 0, 0, 0);
      }
    }
  }

  int chunk = blockIdx.y * 2 + wc;
#pragma unroll
  for (int i = 0; i < 4; ++i) {
    float mm = -1e30f;
#pragma unroll
    for (int vt = 0; vt < 4; ++vt) mm = fmaxf(mm, acc[vt][i]);
#pragma unroll
    for (int o = 1; o < 16; o <<= 1) mm = fmaxf(mm, __shfl_xor(mm, o, 64));
    float ss = 0.f;
#pragma unroll
    for (int vt = 0; vt < 4; ++vt) ss += __expf(acc[vt][i] - mm);
#pragma unroll
    for (int o = 1; o < 16; o <<= 1) ss += __shfl_xor(ss, o, 64);
    if ((lane & 15) == 0) {
      int row = row0 + wr * 16 + (lane >> 4) * 4 + i;
      hpart[(row * 64 + chunk) * 2]     = mm;
      hpart[(row * 64 + chunk) * 2 + 1] = ss;
    }
  }
}

// --- finish: yk + ylse + sel + tgt + comb + final, fused; grid(8) --------
__global__ __launch_bounds__(256) void k_finish(
    const int* __restrict__ x, const float* __restrict__ embed,
    const float* __restrict__ xks, const float* __restrict__ xkdw,
    const float* __restrict__ xkdb, float* __restrict__ ws,
    float* __restrict__ out) {
  int b = blockIdx.x, t = threadIdx.x, lane = t & 63, w = t >> 6;
  __shared__ float YK[DD];
  __shared__ float rm[4], rv[4];
  __shared__ float ylse_s;
  __shared__ float sel0[64], sel1[64], sel2[64], tg0[64], tg1[64];
  __shared__ float ls0s[64], ls1s[64];

  {
    float acc = xkdb[t];
    const float4* yv4 = (const float4*)(ws + WS_YVEC);
    const float4* w4 = (const float4*)(xkdw + (size_t)t * DD);
    float a = 0.f;
#pragma unroll 8
    for (int k4 = 0; k4 < 64; ++k4) {
      float4 yv = yv4[k4], wv = w4[k4];
      a += yv.x*wv.x + yv.y*wv.y + yv.z*wv.z + yv.w*wv.w;
    }
    YK[t] = acc + a;
  }
  {
    float m = -1e30f, s = 0.f;
    for (int v = t; v < VV; v += 256) {
      float lg = ws[WS_YLOG + v];
      float mn = fmaxf(m, lg);
      s = s * __expf(m - mn) + __expf(lg - mn);
      m = mn;
    }
#pragma unroll
    for (int o = 32; o > 0; o >>= 1) {
      float mo = __shfl_xor(m, o, 64), so = __shfl_xor(s, o, 64);
      float mn = fmaxf(m, mo);
      s = s * __expf(m - mn) + so * __expf(mo - mn);
      m = mn;
    }
    if (lane == 0) { rm[w] = m; rv[w] = s; }
  }
  __syncthreads();
  if (t == 0) {
    float M = fmaxf(fmaxf(rm[0], rm[1]), fmaxf(rm[2], rm[3]));
    float S = rv[0]*__expf(rm[0]-M) + rv[1]*__expf(rm[1]-M) +
              rv[2]*__expf(rm[2]-M) + rv[3]*__expf(rm[3]-M);
    ylse_s = M + logf(S);
  }

  const float* hp = ws + WS_HPART;
  for (int i = 0; i < 16; ++i) {
    int l = w * 16 + i, r = b * 64 + l;
    float4 xs = *(const float4*)&ws[WS_XSA0 + (size_t)r * DD + lane * 4];
    float4 k0 = *(const float4*)&xks[lane * 4];
    float4 k1 = *(const float4*)&xks[DD + lane * 4];
    float4 yk4 = *(const float4*)&YK[lane * 4];
    float s0 = waveSum(xs.x*k0.x + xs.y*k0.y + xs.z*k0.z + xs.w*k0.w);
    float s1 = waveSum(xs.x*k1.x + xs.y*k1.y + xs.z*k1.z + xs.w*k1.w);
    float s2 = waveSum(xs.x*yk4.x + xs.y*yk4.y + xs.z*yk4.z + xs.w*yk4.w);
    int xv = x[r];
    float4 e4 = *(const float4*)&embed[(size_t)xv * DD + lane * 4];
    float4 em = *(const float4*)&ws[WS_EMIT + (size_t)r * DD + lane * 4];
    float4 zr = *(const float4*)&ws[WS_ZE + (size_t)r * DD + lane * 4];
    float t0 = waveSum(em.x*e4.x + em.y*e4.y + em.z*e4.z + em.w*e4.w);
    float t1 = waveSum(zr.x*e4.x + zr.y*e4.y + zr.z*e4.z + zr.w*e4.w);
    float m0 = hp[((size_t)r * 64 + lane) * 2];
    float q0 = hp[((size_t)r * 64 + lane) * 2 + 1];
    float m1 = hp[((size_t)(RR + r) * 64 + lane) * 2];
    float q1 = hp[((size_t)(RR + r) * 64 + lane) * 2 + 1];
#pragma unroll
    for (int o = 32; o > 0; o >>= 1) {
      float mo = __shfl_xor(m0, o, 64), so = __shfl_xor(q0, o, 64);
      float mn = fmaxf(m0, mo);
      q0 = q0 * __expf(m0 - mn) + so * __expf(mo - mn);
      m0 = mn;
      mo = __shfl_xor(m1, o, 64); so = __shfl_xor(q1, o, 64);
      mn = fmaxf(m1, mo);
      q1 = q1 * __expf(m1 - mn) + so * __expf(mo - mn);
      m1 = mn;
    }
    if (lane == 0) {
      sel0[l] = s0; sel1[l] = s1; sel2[l] = s2;
      tg0[l] = t0; tg1[l] = t1;
      ls0s[l] = m0 + logf(q0);
      ls1s[l] = m1 + logf(q1);
    }
  }
  __syncthreads();
  if (w == 0) {
    int l = lane, r = b * 64 + l;
    float s0 = sel0[l], s1 = sel1[l], s2 = sel2[l];
    float mx = fmaxf(s0, fmaxf(s1, s2));
    float den = expf(s0 - mx) + expf(s1 - mx) + 64.f * expf(s2 - mx);
    float lsel = mx + logf(den);
    int xv = x[r];
    float P0 = expf(s0 - lsel + tg0[l] - ls0s[l]);
    float P1 = expf(s1 - lsel + tg1[l] - ls1s[l]);
    float Py = expf(s2 - lsel + ws[WS_YLOG + xv] - ylse_s);
    float cent = sqrtf(P0 + P1 + 64.f * Py);
    float sum = waveSum(cent);
    if (lane == 0) out[b] = -(sum * (1.0f / 64.f));
  }
}

extern "C" void kernel_launch(void* const* d_in, const int* in_sizes, int n_in,
                              void* d_out, int out_size, void* d_ws, size_t ws_size,
                              hipStream_t stream) {
  (void)in_sizes; (void)n_in; (void)out_size; (void)ws_size;
  const int*   x     = (const int*)d_in[0];
  const int*   z     = (const int*)d_in[1];
  const float* embed = (const float*)d_in[2];
  const float* initw = (const float*)d_in[3];
  const float* tw    = (const float*)d_in[4];
  const float* tb    = (const float*)d_in[5];
  const float* cw    = (const float*)d_in[6];
  const float* uw    = (const float*)d_in[7];
  const float* xks   = (const float*)d_in[8];
  const float* xkdw  = (const float*)d_in[9];
  const float* xkdb  = (const float*)d_in[10];
  const float* emiw  = (const float*)d_in[11];
  const float* emib  = (const float*)d_in[12];
  float* ws  = (float*)d_ws;
  float* out = (float*)d_out;

  hipLaunchKernelGGL(k_norm_rows, dim3(RR + 2), dim3(256), 0, stream, z, embed, initw, ws);
  hipLaunchKernelGGL(k_rowmat2,   dim3(256),    dim3(256), 0, stream,
                     ws + WS_ZE, uw, tb, ws + WS_ZEU3, 1.0f / 3.0f);
  hipLaunchKernelGGL(k_tr2,       dim3(256),    dim3(256), 0, stream, tw, cw, ws);
  hipLaunchKernelGGL(k_zmat2,     dim3(256),    dim3(256), 0, stream, tw, ws);
  hipLaunchKernelGGL(k_build_w2,  dim3(256),    dim3(256), 0, stream, tw, cw, ws);
  hipLaunchKernelGGL(k_split_e,   dim3(1024),   dim3(256), 0, stream, embed,
                     (unsigned short*)(ws + WS_EHI), (unsigned short*)(ws + WS_ELO));
  hipLaunchKernelGGL(k_ylog,      dim3(64),     dim3(256), 0, stream, embed, ws);

  hipLaunchKernelGGL(k_zero_cnt, dim3(8), dim3(256), 0, stream, (int*)(ws + WS_TOKS));
  hipLaunchKernelGGL(k_scan, dim3(512), dim3(256), 0, stream, ws);

  hipLaunchKernelGGL(k_rowmat2, dim3(256), dim3(256), 0, stream,
                     ws + WS_XSA0, emiw, emib, ws + WS_EMIT, 1.0f);
  hipLaunchKernelGGL(k_head_mfma, dim3(32, 32), dim3(256), 0, stream,
                     ws + WS_EMIT, ws + WS_ZE,
                     (const unsigned short*)(ws + WS_EHI),
                     (const unsigned short*)(ws + WS_ELO),
                     ws + WS_HPART);
  hipLaunchKernelGGL(k_finish, dim3(8), dim3(256), 0, stream,
                     x, embed, xks, xkdw, xkdb, ws, out);
}

// Round 12
// 353.368 us; speedup vs baseline: 4.7454x; 1.0414x over previous
//
#include <hip/hip_runtime.h>
#include <hip/hip_bf16.h>
#include <math.h>

#define BB 8
#define LL 64
#define DD 256
#define VV 4096
#define RR 512           // BB*LL
#define K3 768

typedef __attribute__((ext_vector_type(4))) float f32x4;
typedef __attribute__((ext_vector_type(8))) short bf16x8;
typedef __attribute__((ext_vector_type(4))) unsigned short u16x4;
typedef unsigned long long u64;

// ---- workspace layout (float offsets) -----------------------------------
#define WS_ZE      0
#define WS_ZEU3    (WS_ZE + RR*DD)           // z; then M5 parts 3,4
#define WS_WCT     (WS_ZEU3 + RR*DD)         // M5 parts 0,1,2
#define WS_XSA0    (WS_WCT + DD*K3)          // scan ping (twT/cwT pre-scan)
#define WS_XSA1    (WS_XSA0 + RR*DD)         // scan pong (z2 at scan start)
#define WS_EMIT    (WS_XSA1 + RR*DD)
#define WS_YVEC    (WS_EMIT + RR*DD)
#define WS_X0VEC   (WS_YVEC + DD)
#define WS_YK      (WS_X0VEC + DD)
#define WS_YLOG    (WS_YK + DD)
#define WS_YLSE    (WS_YLOG + VV)
#define WS_SEL     (WS_YLSE + 8)
#define WS_TOKS    WS_SEL                    // 64 lines x 32 ints
#define WS_HPART   WS_WCT                    // head partials overlay (post-scan)
// temp (pre-scan only), inside XSA0:
#define WS_TWT     WS_XSA0                   // tw^T
#define WS_CWT     (WS_XSA0 + 65536)         // cw^T
// MFMA tail:
#define WS_EHI     861184
#define WS_ELO     (WS_EHI + VV*DD/2)

__device__ __forceinline__ float waveSum(float v) {
#pragma unroll
  for (int o = 32; o > 0; o >>= 1) v += __shfl_xor(v, o, 64);
  return v;
}

__device__ __forceinline__ unsigned short f2bf(float f) {
  unsigned int u = __float_as_uint(f);
  unsigned int r = (u + 0x7fffu + ((u >> 16) & 1u)) >> 16;
  return (unsigned short)r;
}
__device__ __forceinline__ float bf2f(unsigned short h) {
  return __uint_as_float(((unsigned int)h) << 16);
}

union U64F2 { u64 u; float f[2]; };

// --- prep1: norm_rows (blocks 0..513) + transposes (514..769) ------------
__global__ __launch_bounds__(256) void k_prep1(
    const int* __restrict__ z, const float* __restrict__ embed,
    const float* __restrict__ initw, const float* __restrict__ tw,
    const float* __restrict__ cw, float* __restrict__ ws) {
  int bid = blockIdx.x, d = threadIdx.x;
  __shared__ float red[4];
  if (bid < RR + 2) {
    float a; float* dst;
    if (bid < RR) { int tok = z[bid]; a = embed[tok * DD + d]; dst = ws + WS_ZE + bid * DD; }
    else if (bid == RR) { a = embed[d]; dst = ws + WS_YVEC; }
    else { a = initw[d * 16]; dst = ws + WS_X0VEC; }
    int lane = d & 63, w = d >> 6;
    float s = waveSum(a);
    __syncthreads();
    if (lane == 0) red[w] = s;
    __syncthreads();
    float sum = red[0] + red[1] + red[2] + red[3];
    float sq = waveSum(a * a);
    __syncthreads();
    if (lane == 0) red[w] = sq;
    __syncthreads();
    float sqs = red[0] + red[1] + red[2] + red[3];
    float mean = sum * (1.0f / DD);
    float var = fmaxf((sqs - (float)DD * mean * mean) * (1.0f / (DD - 1)), 0.0f);
    dst[d] = a / (1e-5f + sqrtf(var));
  } else {
    int c = bid - (RR + 2);
    ws[WS_TWT + c * DD + d] = tw[d * DD + c];
    ws[WS_CWT + c * DD + d] = cw[d * DD + c];
  }
}

// --- out[r][d] = scale*(in[r]·W[d,:] + bias[d]) ; 2 rows / block ----------
__global__ __launch_bounds__(256) void k_rowmat2(
    const float* __restrict__ in, const float* __restrict__ W,
    const float* __restrict__ bias, float* __restrict__ out, float scale) {
  int r0 = blockIdx.x * 2, d = threadIdx.x;
  __shared__ float u[2][260];
  u[0][d] = in[r0 * DD + d];
  u[1][d] = in[(r0 + 1) * DD + d];
  __syncthreads();
  float a0 = 0.f, a1 = 0.f;
  const float4* w4 = (const float4*)(W + d * DD);
  const float4* u0 = (const float4*)&u[0][0];
  const float4* u1 = (const float4*)&u[1][0];
#pragma unroll 8
  for (int k4 = 0; k4 < 64; k4++) {
    float4 w = w4[k4], x0 = u0[k4], x1 = u1[k4];
    a0 += x0.x*w.x + x0.y*w.y + x0.z*w.z + x0.w*w.w;
    a1 += x1.x*w.x + x1.y*w.y + x1.z*w.z + x1.w*w.w;
  }
  float b = bias[d];
  out[r0 * DD + d]       = (a0 + b) * scale;
  out[(r0 + 1) * DD + d] = (a1 + b) * scale;
}

// --- prep3: zmat2 (0..255) + build_w2 (256..511) + zero_cnt (512..519) ---
__global__ __launch_bounds__(256) void k_prep3(
    const float* __restrict__ tw, const float* __restrict__ cw,
    float* __restrict__ ws) {
  int bid = blockIdx.x, c = threadIdx.x;
  __shared__ float zs[4][260];
  __shared__ float rA[DD], rB[DD], rC[DD];
  if (bid < 256) {
    // z2[l] = (z[l-1]@A + z[l+1]@B + z[l]@C)*1 + z[l]  (A=tw/3,B=twT/3,C=cw/3)
    int r0 = bid * 2;
    int b = r0 >> 6, l = r0 & 63;
    const float* zb = ws + WS_ZEU3 + (size_t)b * 64 * DD;
    float* zout = ws + WS_XSA1;
#pragma unroll
    for (int j = 0; j < 4; ++j) {
      int ll = (l + j - 1 + 64) & 63;
      zs[j][c] = zb[ll * DD + c];
    }
    __syncthreads();
    const float4* wA = (const float4*)(ws + WS_TWT + (size_t)c * DD);
    const float4* wB = (const float4*)(tw + (size_t)c * DD);
    const float4* wC = (const float4*)(ws + WS_CWT + (size_t)c * DD);
    const float4* zm0 = (const float4*)&zs[0][0];
    const float4* z00 = (const float4*)&zs[1][0];
    const float4* zp0 = (const float4*)&zs[2][0];
    const float4* zp1 = (const float4*)&zs[3][0];
    float a0 = 0.f, a1 = 0.f;
#pragma unroll 8
    for (int k4 = 0; k4 < 64; ++k4) {
      float4 A4 = wA[k4], B4 = wB[k4], C4 = wC[k4];
      float4 m0 = zm0[k4], z0 = z00[k4], p0 = zp0[k4], p1 = zp1[k4];
      a0 += m0.x*A4.x + m0.y*A4.y + m0.z*A4.z + m0.w*A4.w
          + p0.x*B4.x + p0.y*B4.y + p0.z*B4.z + p0.w*B4.w
          + z0.x*C4.x + z0.y*C4.y + z0.z*C4.z + z0.w*C4.w;
      a1 += z0.x*A4.x + z0.y*A4.y + z0.z*A4.z + z0.w*A4.w
          + p1.x*B4.x + p1.y*B4.y + p1.z*B4.z + p1.w*B4.w
          + p0.x*C4.x + p0.y*C4.y + p0.z*C4.z + p0.w*C4.w;
    }
    const float inv3 = 1.0f / 3.0f;
    zout[(size_t)r0 * DD + c]       = a0 * inv3 + zs[1][c];
    zout[(size_t)(r0 + 1) * DD + c] = a1 * inv3 + zs[2][c];
  } else if (bid < 512) {
    // M-2=A2, M-1=CA+AC, M0=BA+AB+C2, M+1=CB+BC, M+2=B2
    int k = bid - 256;
    const float* twT = ws + WS_TWT;
    const float inv9 = 1.0f / 9.0f;
    rA[c] = tw[k * DD + c] * inv9;
    rB[c] = twT[k * DD + c] * inv9;
    rC[c] = cw[k * DD + c] * inv9;
    __syncthreads();
    float a2 = 0.f, m1 = 0.f, m0 = 0.f, m3 = 0.f, b2 = 0.f;
#pragma unroll 4
    for (int j = 0; j < DD; ++j) {
      float Aj = tw[j * DD + c];
      float Bj = twT[j * DD + c];
      float Cj = cw[j * DD + c];
      float ra = rA[j], rb = rB[j], rc = rC[j];
      a2 += ra * Aj;
      m1 += rc * Aj + ra * Cj;
      m0 += rb * Aj + ra * Bj + rc * Cj;
      m3 += rc * Bj + rb * Cj;
      b2 += rb * Bj;
    }
    float* p0 = ws + WS_WCT;
    float* p3 = ws + WS_ZEU3;
    p0[k * DD + c]               = a2;
    p0[65536 + k * DD + c]       = m1;
    p0[2 * 65536 + k * DD + c]   = m0;
    p3[k * DD + c]               = m3;
    p3[65536 + k * DD + c]       = b2;
  } else {
    ((int*)(ws + WS_TOKS))[(bid - 512) * 256 + c] = 0;
  }
}

// --- scan_big: scan+emit (0..511) | split_e (512..1535) | ylog (1536..1599)
// Scan: 32 squared steps, 8 rows x 32 cols/block, W (K=1280) in 40 f32x4.
// Extras are data-independent of the scan and hide under its sync stalls.
// Scan blocks are IDs 0..511 -> dispatched (and resident) first; extras
// never wait on anything, so pending scan blocks always make progress.
__global__ __launch_bounds__(256, 2) void k_scan_big(
    float* __restrict__ ws, const float* __restrict__ embed,
    const float* __restrict__ emiw, const float* __restrict__ emib) {
  const int bid = blockIdx.x;
  const int t = threadIdx.x, lane = t & 63;

  __shared__ float S[12 * 264];
  __shared__ float PAR[32 * 260];
  __shared__ float PAR2[4 * 256];
  __shared__ float ZB[256];

  if (bid >= 512) {
    int eb = bid - 512;
    if (eb < 1024) {           // ---- split_e ----
      unsigned short* eh = (unsigned short*)(ws + WS_EHI);
      unsigned short* el = (unsigned short*)(ws + WS_ELO);
      int i = (eb * 256 + t) * 4;
      float4 v = *(const float4*)(embed + i);
      float f[4] = {v.x, v.y, v.z, v.w};
      u16x4 h, l;
#pragma unroll
      for (int j = 0; j < 4; ++j) {
        unsigned short hb = f2bf(f[j]);
        h[j] = hb;
        l[j] = f2bf(f[j] - bf2f(hb));
      }
      *(u16x4*)(eh + i) = h;
      *(u16x4*)(el + i) = l;
    } else {                   // ---- ylog ----
      int yb = eb - 1024;
      float* y = S;
      y[t] = ws[WS_YVEC + t];
      __syncthreads();
      int w = t >> 6;
      for (int i = 0; i < 16; i++) {
        int v = yb * 64 + i * 4 + w;
        float p = 0.f;
#pragma unroll
        for (int j = 0; j < 4; j++)
          p += y[lane + 64*j] * embed[(size_t)v * DD + lane + 64*j];
        p = waveSum(p);
        if (lane == 0) ws[WS_YLOG + v] = p;
      }
    }
    return;
  }

  // ------------------------- scan role ------------------------------------
  const int rg = bid & 63, cg = bid >> 6;
  const int b = rg >> 3, rgl = rg & 7, l0 = rgl * 8;
  const int cl = t & 7, rs = t >> 3;
  const int c0 = cg * 32 + cl * 4;

  int* tok = (int*)(ws + WS_TOKS);

  const float* Wp[5] = {ws + WS_WCT, ws + WS_WCT + 65536, ws + WS_WCT + 2*65536,
                        ws + WS_ZEU3, ws + WS_ZEU3 + 65536};
  f32x4 wreg[40];
#pragma unroll
  for (int p = 0; p < 5; ++p)
#pragma unroll
    for (int q = 0; q < 2; ++q)
#pragma unroll
      for (int kk = 0; kk < 4; ++kk)
        wreg[p * 8 + q * 4 + kk] =
            *(const f32x4*)&Wp[p][(size_t)(rs * 8 + q * 4 + kk) * DD + c0];

  { // z2 tile from XSA1 (pre-scan by prep3-zmat2)
    int r = t >> 5, c = t & 31;
    ZB[r * 32 + c] = ws[WS_XSA1 + (size_t)(b * 64 + l0 + r) * DD + cg * 32 + c];
  }

  const int nb0 = b * 8 + ((rgl + 7) & 7);
  const int nb1 = b * 8 + rgl;
  const int nb2 = b * 8 + ((rgl + 1) & 7);
  const int myl = (lane == 0) ? nb0 : (lane == 1) ? nb1 : nb2;

  for (int st = 0; st < 32; ++st) {
    const float* xin  = ws + ((st & 1) ? WS_XSA1 : WS_XSA0);
    float*       xout = ws + ((st & 1) ? WS_XSA0 : WS_XSA1);

    if (st > 0) {
      const int tg = st << 3;
      while (true) {
        int v = __hip_atomic_load(tok + myl * 32, __ATOMIC_RELAXED,
                                  __HIP_MEMORY_SCOPE_AGENT);
        if (__all(v >= tg)) break;
        __builtin_amdgcn_s_sleep(1);
      }
    }

    // stage 12 rows x 256 f (1536 u64, 6/thread); st=0 -> x0vec broadcast
#pragma unroll
    for (int it = 0; it < 6; ++it) {
      int idx = it * 256 + t;
      int j = idx >> 7;
      int kk = (idx & 127) << 1;
      const u64* src = (st == 0)
          ? (const u64*)(ws + WS_X0VEC + kk)
          : (const u64*)(xin + (size_t)(b * 64 + ((l0 + j - 2 + 64) & 63)) * DD + kk);
      u64 v = __hip_atomic_load(src, __ATOMIC_RELAXED, __HIP_MEMORY_SCOPE_AGENT);
      *(u64*)(&S[j * 264 + kk]) = v;
    }
    __syncthreads();

    f32x4 acc[8];
#pragma unroll
    for (int r = 0; r < 8; ++r) acc[r] = (f32x4){0.f, 0.f, 0.f, 0.f};

#pragma unroll
    for (int p = 0; p < 5; ++p) {
#pragma unroll
      for (int r = 0; r < 8; ++r) {
        int j = r + p;
#pragma unroll
        for (int q = 0; q < 2; ++q) {
          f32x4 xv = *(const f32x4*)&S[j * 264 + rs * 8 + q * 4];
          acc[r] += xv.x * wreg[p * 8 + q * 4 + 0];
          acc[r] += xv.y * wreg[p * 8 + q * 4 + 1];
          acc[r] += xv.z * wreg[p * 8 + q * 4 + 2];
          acc[r] += xv.w * wreg[p * 8 + q * 4 + 3];
        }
      }
    }

#pragma unroll
    for (int r = 0; r < 8; ++r)
      *(f32x4*)&PAR[rs * 260 + r * 32 + cl * 4] = acc[r];
    __syncthreads();

    {
      int u = t & 63, v = t >> 6;
      f32x4 s4 = (f32x4){0.f, 0.f, 0.f, 0.f};
#pragma unroll
      for (int i = 0; i < 8; ++i)
        s4 += *(const f32x4*)&PAR[(v * 8 + i) * 260 + u * 4];
      *(f32x4*)&PAR2[v * 256 + u * 4] = s4;
    }
    __syncthreads();

    if (t < 64) {
      int r = t >> 3, c8 = t & 7;
      f32x4 s4 = (f32x4){0.f, 0.f, 0.f, 0.f};
#pragma unroll
      for (int v = 0; v < 4; ++v)
        s4 += *(const f32x4*)&PAR2[v * 256 + t * 4];
      f32x4 zb = *(const f32x4*)&ZB[r * 32 + c8 * 4];
      s4 += zb;
      size_t off = (size_t)(b * 64 + l0 + r) * DD + cg * 32 + c8 * 4;
      U64F2 lo, hi;
      lo.f[0] = s4.x; lo.f[1] = s4.y;
      hi.f[0] = s4.z; hi.f[1] = s4.w;
      __hip_atomic_store((u64*)(xout + off),     lo.u, __ATOMIC_RELAXED, __HIP_MEMORY_SCOPE_AGENT);
      __hip_atomic_store((u64*)(xout + off + 2), hi.u, __ATOMIC_RELAXED, __HIP_MEMORY_SCOPE_AGENT);
    }

    __syncthreads();   // drains vmcnt(0): bypass stores visible first
    if (t == 0)
      __hip_atomic_fetch_add(tok + nb1 * 32, 1, __ATOMIC_RELAXED,
                             __HIP_MEMORY_SCOPE_AGENT);
  }

  // ---- emit tail: this block's 8 rows x 32 cols of emit = xsa@emiw^T + b --
  if (t == 0) {
    while (__hip_atomic_load(tok + nb1 * 32, __ATOMIC_RELAXED,
                             __HIP_MEMORY_SCOPE_AGENT) < 256)
      __builtin_amdgcn_s_sleep(1);
  }
  __syncthreads();
#pragma unroll
  for (int it = 0; it < 4; ++it) {
    int idx = it * 256 + t;
    int j = idx >> 7;
    int kk = (idx & 127) << 1;
    u64 v = __hip_atomic_load(
        (const u64*)(ws + WS_XSA0 + (size_t)(b * 64 + l0 + j) * DD + kk),
        __ATOMIC_RELAXED, __HIP_MEMORY_SCOPE_AGENT);
    *(u64*)(&S[j * 264 + kk]) = v;
  }
  __syncthreads();
  {
    int r = t >> 5, c = cg * 32 + (t & 31);
    const float4* wv = (const float4*)(emiw + (size_t)c * DD);
    const float4* xv = (const float4*)&S[r * 264];
    float a = 0.f;
#pragma unroll 8
    for (int k4 = 0; k4 < 64; ++k4) {
      float4 w = wv[k4], x = xv[k4];
      a += x.x*w.x + x.y*w.y + x.z*w.z + x.w*w.w;
    }
    ws[WS_EMIT + (size_t)(b * 64 + l0 + r) * DD + c] = a + emib[c];
  }
}

// --- head GEMM via MFMA, split-precision bf16, in-LDS U split ------------
__global__ __launch_bounds__(256) void k_head_mfma(
    const float* __restrict__ uemit, const float* __restrict__ uze,
    const unsigned short* __restrict__ eh, const unsigned short* __restrict__ el,
    float* __restrict__ hpart) {
  int row0 = blockIdx.x * 32;
  int v0 = blockIdx.y * 128;
  int t = threadIdx.x, lane = t & 63, w = t >> 6;
  int wr = w >> 1, wc = w & 1;
  __shared__ unsigned short UH[32 * 264];
  __shared__ unsigned short UL[32 * 264];
  const float* src = (row0 < RR) ? (uemit + (size_t)row0 * DD)
                                 : (uze + (size_t)(row0 - RR) * DD);
#pragma unroll
  for (int it = 0; it < 4; ++it) {
    int r = it * 8 + (t >> 5);
    int c8 = (t & 31) * 8;
    float4 a = *(const float4*)(src + (size_t)r * DD + c8);
    float4 b2 = *(const float4*)(src + (size_t)r * DD + c8 + 4);
    float fa[8] = {a.x, a.y, a.z, a.w, b2.x, b2.y, b2.z, b2.w};
    u16x4 h0, l0v, h1, l1;
#pragma unroll
    for (int j = 0; j < 4; ++j) {
      unsigned short hb = f2bf(fa[j]);
      h0[j] = hb; l0v[j] = f2bf(fa[j] - bf2f(hb));
      unsigned short hb1 = f2bf(fa[4 + j]);
      h1[j] = hb1; l1[j] = f2bf(fa[4 + j] - bf2f(hb1));
    }
    *(u16x4*)(&UH[r * 264 + c8])     = h0;
    *(u16x4*)(&UH[r * 264 + c8 + 4]) = h1;
    *(u16x4*)(&UL[r * 264 + c8])     = l0v;
    *(u16x4*)(&UL[r * 264 + c8 + 4]) = l1;
  }
  __syncthreads();

  f32x4 acc[4];
#pragma unroll
  for (int q = 0; q < 4; ++q) acc[q] = (f32x4){0.f, 0.f, 0.f, 0.f};

  int arow = wr * 16 + (lane & 15);
  int kof = 8 * (lane >> 4);
  const unsigned short* Ah = &UH[arow * 264 + kof];
  const unsigned short* Al = &UL[arow * 264 + kof];
  int vbase = v0 + wc * 64 + (lane & 15);

#pragma unroll
  for (int p = 0; p < 3; ++p) {
    const unsigned short* Ab = (p == 2) ? Al : Ah;
    const unsigned short* Ebl = ((p == 1) ? el : eh) + (size_t)vbase * DD + kof;
#pragma unroll
    for (int ks = 0; ks < 8; ++ks) {
      int k0 = ks * 32;
      bf16x8 a = *(const bf16x8*)(Ab + k0);
#pragma unroll
      for (int vt = 0; vt < 4; ++vt) {
        bf16x8 bfr = *(const bf16x8*)(Ebl + vt * 16 * DD + k0);
        acc[vt] = __builtin_amdgcn_mfma_f32_16x16x32_bf16(a, bfr, acc[vt], 0, 0, 0);
      }
    }
  }

  int chunk = blockIdx.y * 2 + wc;
#pragma unroll
  for (int i = 0; i < 4; ++i) {
    float mm = -1e30f;
#pragma unroll
    for (int vt = 0; vt < 4; ++vt) mm = fmaxf(mm, acc[vt][i]);
#pragma unroll
    for (int o = 1; o < 16; o <<= 1) mm = fmaxf(mm, __shfl_xor(mm, o, 64));
    float ss = 0.f;
#pragma unroll
    for (int vt = 0; vt < 4; ++vt) ss += __expf(acc[vt][i] - mm);
#pragma unroll
    for (int o = 1; o < 16; o <<= 1) ss += __shfl_xor(ss, o, 64);
    if ((lane & 15) == 0) {
      int row = row0 + wr * 16 + (lane >> 4) * 4 + i;
      hpart[(row * 64 + chunk) * 2]     = mm;
      hpart[(row * 64 + chunk) * 2 + 1] = ss;
    }
  }
}

// --- finish: yk + ylse + sel + tgt + comb + final, fused; grid(8) --------
__global__ __launch_bounds__(256) void k_finish(
    const int* __restrict__ x, const float* __restrict__ embed,
    const float* __restrict__ xks, const float* __restrict__ xkdw,
    const float* __restrict__ xkdb, float* __restrict__ ws,
    float* __restrict__ out) {
  int b = blockIdx.x, t = threadIdx.x, lane = t & 63, w = t >> 6;
  __shared__ float YK[DD];
  __shared__ float rm[4], rv[4];
  __shared__ float ylse_s;
  __shared__ float sel0[64], sel1[64], sel2[64], tg0[64], tg1[64];
  __shared__ float ls0s[64], ls1s[64];

  {
    float acc = xkdb[t];
    const float4* yv4 = (const float4*)(ws + WS_YVEC);
    const float4* w4 = (const float4*)(xkdw + (size_t)t * DD);
    float a = 0.f;
#pragma unroll 8
    for (int k4 = 0; k4 < 64; ++k4) {
      float4 yv = yv4[k4], wv = w4[k4];
      a += yv.x*wv.x + yv.y*wv.y + yv.z*wv.z + yv.w*wv.w;
    }
    YK[t] = acc + a;
  }
  {
    float m = -1e30f, s = 0.f;
    for (int v = t; v < VV; v += 256) {
      float lg = ws[WS_YLOG + v];
      float mn = fmaxf(m, lg);
      s = s * __expf(m - mn) + __expf(lg - mn);
      m = mn;
    }
#pragma unroll
    for (int o = 32; o > 0; o >>= 1) {
      float mo = __shfl_xor(m, o, 64), so = __shfl_xor(s, o, 64);
      float mn = fmaxf(m, mo);
      s = s * __expf(m - mn) + so * __expf(mo - mn);
      m = mn;
    }
    if (lane == 0) { rm[w] = m; rv[w] = s; }
  }
  __syncthreads();
  if (t == 0) {
    float M = fmaxf(fmaxf(rm[0], rm[1]), fmaxf(rm[2], rm[3]));
    float S = rv[0]*__expf(rm[0]-M) + rv[1]*__expf(rm[1]-M) +
              rv[2]*__expf(rm[2]-M) + rv[3]*__expf(rm[3]-M);
    ylse_s = M + logf(S);
  }

  const float* hp = ws + WS_HPART;
  for (int i = 0; i < 16; ++i) {
    int l = w * 16 + i, r = b * 64 + l;
    float4 xs = *(const float4*)&ws[WS_XSA0 + (size_t)r * DD + lane * 4];
    float4 k0 = *(const float4*)&xks[lane * 4];
    float4 k1 = *(const float4*)&xks[DD + lane * 4];
    float4 yk4 = *(const float4*)&YK[lane * 4];
    float s0 = waveSum(xs.x*k0.x + xs.y*k0.y + xs.z*k0.z + xs.w*k0.w);
    float s1 = waveSum(xs.x*k1.x + xs.y*k1.y + xs.z*k1.z + xs.w*k1.w);
    float s2 = waveSum(xs.x*yk4.x + xs.y*yk4.y + xs.z*yk4.z + xs.w*yk4.w);
    int xv = x[r];
    float4 e4 = *(const float4*)&embed[(size_t)xv * DD + lane * 4];
    float4 em = *(const float4*)&ws[WS_EMIT + (size_t)r * DD + lane * 4];
    float4 zr = *(const float4*)&ws[WS_ZE + (size_t)r * DD + lane * 4];
    float t0 = waveSum(em.x*e4.x + em.y*e4.y + em.z*e4.z + em.w*e4.w);
    float t1 = waveSum(zr.x*e4.x + zr.y*e4.y + zr.z*e4.z + zr.w*e4.w);
    float m0 = hp[((size_t)r * 64 + lane) * 2];
    float q0 = hp[((size_t)r * 64 + lane) * 2 + 1];
    float m1 = hp[((size_t)(RR + r) * 64 + lane) * 2];
    float q1 = hp[((size_t)(RR + r) * 64 + lane) * 2 + 1];
#pragma unroll
    for (int o = 32; o > 0; o >>= 1) {
      float mo = __shfl_xor(m0, o, 64), so = __shfl_xor(q0, o, 64);
      float mn = fmaxf(m0, mo);
      q0 = q0 * __expf(m0 - mn) + so * __expf(mo - mn);
      m0 = mn;
      mo = __shfl_xor(m1, o, 64); so = __shfl_xor(q1, o, 64);
      mn = fmaxf(m1, mo);
      q1 = q1 * __expf(m1 - mn) + so * __expf(mo - mn);
      m1 = mn;
    }
    if (lane == 0) {
      sel0[l] = s0; sel1[l] = s1; sel2[l] = s2;
      tg0[l] = t0; tg1[l] = t1;
      ls0s[l] = m0 + logf(q0);
      ls1s[l] = m1 + logf(q1);
    }
  }
  __syncthreads();
  if (w == 0) {
    int l = lane, r = b * 64 + l;
    float s0 = sel0[l], s1 = sel1[l], s2 = sel2[l];
    float mx = fmaxf(s0, fmaxf(s1, s2));
    float den = expf(s0 - mx) + expf(s1 - mx) + 64.f * expf(s2 - mx);
    float lsel = mx + logf(den);
    int xv = x[r];
    float P0 = expf(s0 - lsel + tg0[l] - ls0s[l]);
    float P1 = expf(s1 - lsel + tg1[l] - ls1s[l]);
    float Py = expf(s2 - lsel + ws[WS_YLOG + xv] - ylse_s);
    float cent = sqrtf(P0 + P1 + 64.f * Py);
    float sum = waveSum(cent);
    if (lane == 0) out[b] = -(sum * (1.0f / 64.f));
  }
}

extern "C" void kernel_launch(void* const* d_in, const int* in_sizes, int n_in,
                              void* d_out, int out_size, void* d_ws, size_t ws_size,
                              hipStream_t stream) {
  (void)in_sizes; (void)n_in; (void)out_size; (void)ws_size;
  const int*   x     = (const int*)d_in[0];
  const int*   z     = (const int*)d_in[1];
  const float* embed = (const float*)d_in[2];
  const float* initw = (const float*)d_in[3];
  const float* tw    = (const float*)d_in[4];
  const float* tb    = (const float*)d_in[5];
  const float* cw    = (const float*)d_in[6];
  const float* uw    = (const float*)d_in[7];
  const float* xks   = (const float*)d_in[8];
  const float* xkdw  = (const float*)d_in[9];
  const float* xkdb  = (const float*)d_in[10];
  const float* emiw  = (const float*)d_in[11];
  const float* emib  = (const float*)d_in[12];
  float* ws  = (float*)d_ws;
  float* out = (float*)d_out;

  // P1: norm rows + transposes (independent, input-only reads)
  hipLaunchKernelGGL(k_prep1, dim3(RR + 2 + 256), dim3(256), 0, stream,
                     z, embed, initw, tw, cw, ws);
  // P2: zeu3 = (ze @ uw^T + tb)/3
  hipLaunchKernelGGL(k_rowmat2, dim3(256), dim3(256), 0, stream,
                     ws + WS_ZE, uw, tb, ws + WS_ZEU3, 1.0f / 3.0f);
  // P3: z2 + squared-operator matrices + token zero
  hipLaunchKernelGGL(k_prep3, dim3(520), dim3(256), 0, stream, tw, cw, ws);
  // SCAN (blocks 0..511) + concurrent split_e/ylog (512..1599) + emit tail
  hipLaunchKernelGGL(k_scan_big, dim3(1600), dim3(256), 0, stream,
                     ws, embed, emiw, emib);
  // Head + finish
  hipLaunchKernelGGL(k_head_mfma, dim3(32, 32), dim3(256), 0, stream,
                     ws + WS_EMIT, ws + WS_ZE,
                     (const unsigned short*)(ws + WS_EHI),
                     (const unsigned short*)(ws + WS_ELO),
                     ws + WS_HPART);
  hipLaunchKernelGGL(k_finish, dim3(8), dim3(256), 0, stream,
                     x, embed, xks, xkdw, xkdb, ws, out);
}

// Round 13
// 351.988 us; speedup vs baseline: 4.7640x; 1.0039x over previous
//
#include <hip/hip_runtime.h>
#include <hip/hip_bf16.h>
#include <math.h>

#define BB 8
#define LL 64
#define DD 256
#define VV 4096
#define RR 512           // BB*LL
#define K3 768

typedef __attribute__((ext_vector_type(4))) float f32x4;
typedef __attribute__((ext_vector_type(8))) short bf16x8;
typedef __attribute__((ext_vector_type(4))) unsigned short u16x4;
typedef unsigned long long u64;

// ---- workspace layout (float offsets) -----------------------------------
#define WS_ZE      0
#define WS_ZEU3    (WS_ZE + RR*DD)           // z; then M5 parts 3,4
#define WS_WCT     (WS_ZEU3 + RR*DD)         // M5 parts 0,1,2
#define WS_XSA0    (WS_WCT + DD*K3)          // scan ping (twT/cwT pre-scan)
#define WS_XSA1    (WS_XSA0 + RR*DD)         // scan pong (z2 at scan start)
#define WS_EMIT    (WS_XSA1 + RR*DD)
#define WS_YVEC    (WS_EMIT + RR*DD)
#define WS_X0VEC   (WS_YVEC + DD)
#define WS_YK      (WS_X0VEC + DD)
#define WS_YLOG    (WS_YK + DD)
#define WS_YLSE    (WS_YLOG + VV)
#define WS_SEL     (WS_YLSE + 8)
#define WS_TOKS    WS_SEL                    // 64 lines x 32 ints
// temp (pre-scan only), inside XSA0:
#define WS_TWT     WS_XSA0                   // tw^T
#define WS_CWT     (WS_XSA0 + 65536)         // cw^T
// MFMA tail:
#define WS_EHI     861184
#define WS_ELO     (WS_EHI + VV*DD/2)
#define WS_HPHI    (WS_ELO + VV*DD/2)        // 1,909,760: gated HPART (fresh)
#define WS_BIG_FLOATS (WS_HPHI + 1024*64*2)  // 2,040,832 floats = 8,163,328 B

__device__ __forceinline__ float waveSum(float v) {
#pragma unroll
  for (int o = 32; o > 0; o >>= 1) v += __shfl_xor(v, o, 64);
  return v;
}

__device__ __forceinline__ unsigned short f2bf(float f) {
  unsigned int u = __float_as_uint(f);
  unsigned int r = (u + 0x7fffu + ((u >> 16) & 1u)) >> 16;
  return (unsigned short)r;
}
__device__ __forceinline__ float bf2f(unsigned short h) {
  return __uint_as_float(((unsigned int)h) << 16);
}

union U64F2 { u64 u; float f[2]; };

// --- shared head tile: 32 rows x 128 v, split-bf16 MFMA, online (m,s) ----
__device__ __forceinline__ void head_tile(
    int row0, int vy, const float* __restrict__ uemit,
    const float* __restrict__ uze,
    const unsigned short* __restrict__ eh, const unsigned short* __restrict__ el,
    float* __restrict__ hpart, float* shbuf, int t) {
  unsigned short* UH = (unsigned short*)shbuf;
  unsigned short* UL = UH + 32 * 264;
  int lane = t & 63, w = t >> 6;
  int wr = w >> 1, wc = w & 1;
  const float* src = (row0 < RR) ? (uemit + (size_t)row0 * DD)
                                 : (uze + (size_t)(row0 - RR) * DD);
#pragma unroll
  for (int it = 0; it < 4; ++it) {
    int r = it * 8 + (t >> 5);
    int c8 = (t & 31) * 8;
    float4 a = *(const float4*)(src + (size_t)r * DD + c8);
    float4 b2 = *(const float4*)(src + (size_t)r * DD + c8 + 4);
    float fa[8] = {a.x, a.y, a.z, a.w, b2.x, b2.y, b2.z, b2.w};
    u16x4 h0, l0v, h1, l1;
#pragma unroll
    for (int j = 0; j < 4; ++j) {
      unsigned short hb = f2bf(fa[j]);
      h0[j] = hb; l0v[j] = f2bf(fa[j] - bf2f(hb));
      unsigned short hb1 = f2bf(fa[4 + j]);
      h1[j] = hb1; l1[j] = f2bf(fa[4 + j] - bf2f(hb1));
    }
    *(u16x4*)(&UH[r * 264 + c8])     = h0;
    *(u16x4*)(&UH[r * 264 + c8 + 4]) = h1;
    *(u16x4*)(&UL[r * 264 + c8])     = l0v;
    *(u16x4*)(&UL[r * 264 + c8 + 4]) = l1;
  }
  __syncthreads();

  f32x4 acc[4];
#pragma unroll
  for (int q = 0; q < 4; ++q) acc[q] = (f32x4){0.f, 0.f, 0.f, 0.f};

  int arow = wr * 16 + (lane & 15);
  int kof = 8 * (lane >> 4);
  const unsigned short* Ah = &UH[arow * 264 + kof];
  const unsigned short* Al = &UL[arow * 264 + kof];
  int vbase = vy * 128 + wc * 64 + (lane & 15);

#pragma unroll
  for (int p = 0; p < 3; ++p) {
    const unsigned short* Ab = (p == 2) ? Al : Ah;
    const unsigned short* Ebl = ((p == 1) ? el : eh) + (size_t)vbase * DD + kof;
#pragma unroll
    for (int ks = 0; ks < 8; ++ks) {
      int k0 = ks * 32;
      bf16x8 a = *(const bf16x8*)(Ab + k0);
#pragma unroll
      for (int vt = 0; vt < 4; ++vt) {
        bf16x8 bfr = *(const bf16x8*)(Ebl + vt * 16 * DD + k0);
        acc[vt] = __builtin_amdgcn_mfma_f32_16x16x32_bf16(a, bfr, acc[vt], 0, 0, 0);
      }
    }
  }

  int chunk = vy * 2 + wc;
#pragma unroll
  for (int i = 0; i < 4; ++i) {
    float mm = -1e30f;
#pragma unroll
    for (int vt = 0; vt < 4; ++vt) mm = fmaxf(mm, acc[vt][i]);
#pragma unroll
    for (int o = 1; o < 16; o <<= 1) mm = fmaxf(mm, __shfl_xor(mm, o, 64));
    float ss = 0.f;
#pragma unroll
    for (int vt = 0; vt < 4; ++vt) ss += __expf(acc[vt][i] - mm);
#pragma unroll
    for (int o = 1; o < 16; o <<= 1) ss += __shfl_xor(ss, o, 64);
    if ((lane & 15) == 0) {
      int row = row0 + wr * 16 + (lane >> 4) * 4 + i;
      hpart[((size_t)row * 64 + chunk) * 2]     = mm;
      hpart[((size_t)row * 64 + chunk) * 2 + 1] = ss;
    }
  }
}

// --- prep1: norm (0..513) | transposes (514..769) | split_e (770..1793)
//            | ylog (1794..1857) — all depend only on inputs + yvec -------
__global__ __launch_bounds__(256) void k_prep1(
    const int* __restrict__ z, const float* __restrict__ embed,
    const float* __restrict__ initw, const float* __restrict__ tw,
    const float* __restrict__ cw, float* __restrict__ ws) {
  int bid = blockIdx.x, d = threadIdx.x;
  __shared__ float red[4];
  __shared__ float y[DD];
  if (bid < RR + 2) {
    float a; float* dst;
    if (bid < RR) { int tok = z[bid]; a = embed[tok * DD + d]; dst = ws + WS_ZE + bid * DD; }
    else if (bid == RR) { a = embed[d]; dst = ws + WS_YVEC; }
    else { a = initw[d * 16]; dst = ws + WS_X0VEC; }
    int lane = d & 63, w = d >> 6;
    float s = waveSum(a);
    __syncthreads();
    if (lane == 0) red[w] = s;
    __syncthreads();
    float sum = red[0] + red[1] + red[2] + red[3];
    float sq = waveSum(a * a);
    __syncthreads();
    if (lane == 0) red[w] = sq;
    __syncthreads();
    float sqs = red[0] + red[1] + red[2] + red[3];
    float mean = sum * (1.0f / DD);
    float var = fmaxf((sqs - (float)DD * mean * mean) * (1.0f / (DD - 1)), 0.0f);
    dst[d] = a / (1e-5f + sqrtf(var));
  } else if (bid < RR + 2 + 256) {
    int c = bid - (RR + 2);
    ws[WS_TWT + c * DD + d] = tw[d * DD + c];
    ws[WS_CWT + c * DD + d] = cw[d * DD + c];
  } else if (bid < RR + 2 + 256 + 1024) {
    int eb = bid - (RR + 2 + 256);
    unsigned short* eh = (unsigned short*)(ws + WS_EHI);
    unsigned short* el = (unsigned short*)(ws + WS_ELO);
    int i = (eb * 256 + d) * 4;
    float4 v = *(const float4*)(embed + i);
    float f[4] = {v.x, v.y, v.z, v.w};
    u16x4 h, l;
#pragma unroll
    for (int j = 0; j < 4; ++j) {
      unsigned short hb = f2bf(f[j]);
      h[j] = hb;
      l[j] = f2bf(f[j] - bf2f(hb));
    }
    *(u16x4*)(eh + i) = h;
    *(u16x4*)(el + i) = l;
  } else {
    // ylog: needs yvec (written by block RR of THIS kernel? No —
    // yvec is written by bid==RR in this same dispatch; cross-block dep!)
    // SAFE: yvec is produced by k_prep0 below instead.
    int yb = bid - (RR + 2 + 256 + 1024);
    y[d] = ws[WS_YVEC + d];
    __syncthreads();
    int w = d >> 6, lane = d & 63;
    for (int i = 0; i < 16; i++) {
      int v = yb * 64 + i * 4 + w;
      float p = 0.f;
#pragma unroll
      for (int j = 0; j < 4; j++)
        p += y[lane + 64*j] * embed[(size_t)v * DD + lane + 64*j];
      p = waveSum(p);
      if (lane == 0) ws[WS_YLOG + v] = p;
    }
  }
}

// --- prep0: yvec + x0vec only (so prep1's ylog has yvec ready) -----------
__global__ __launch_bounds__(256) void k_prep0(
    const float* __restrict__ embed, const float* __restrict__ initw,
    float* __restrict__ ws) {
  int r = blockIdx.x, d = threadIdx.x;
  __shared__ float red[4];
  float a = (r == 0) ? embed[d] : initw[d * 16];
  float* dst = ws + ((r == 0) ? WS_YVEC : WS_X0VEC);
  int lane = d & 63, w = d >> 6;
  float s = waveSum(a);
  __syncthreads();
  if (lane == 0) red[w] = s;
  __syncthreads();
  float sum = red[0] + red[1] + red[2] + red[3];
  float sq = waveSum(a * a);
  __syncthreads();
  if (lane == 0) red[w] = sq;
  __syncthreads();
  float sqs = red[0] + red[1] + red[2] + red[3];
  float mean = sum * (1.0f / DD);
  float var = fmaxf((sqs - (float)DD * mean * mean) * (1.0f / (DD - 1)), 0.0f);
  dst[d] = a / (1e-5f + sqrtf(var));
}

// --- out[r][d] = scale*(in[r]·W[d,:] + bias[d]) ; 2 rows / block ----------
__global__ __launch_bounds__(256) void k_rowmat2(
    const float* __restrict__ in, const float* __restrict__ W,
    const float* __restrict__ bias, float* __restrict__ out, float scale) {
  int r0 = blockIdx.x * 2, d = threadIdx.x;
  __shared__ float u[2][260];
  u[0][d] = in[r0 * DD + d];
  u[1][d] = in[(r0 + 1) * DD + d];
  __syncthreads();
  float a0 = 0.f, a1 = 0.f;
  const float4* w4 = (const float4*)(W + d * DD);
  const float4* u0 = (const float4*)&u[0][0];
  const float4* u1 = (const float4*)&u[1][0];
#pragma unroll 8
  for (int k4 = 0; k4 < 64; k4++) {
    float4 w = w4[k4], x0 = u0[k4], x1 = u1[k4];
    a0 += x0.x*w.x + x0.y*w.y + x0.z*w.z + x0.w*w.w;
    a1 += x1.x*w.x + x1.y*w.y + x1.z*w.z + x1.w*w.w;
  }
  float b = bias[d];
  out[r0 * DD + d]       = (a0 + b) * scale;
  out[(r0 + 1) * DD + d] = (a1 + b) * scale;
}

// --- prep3: zmat2 (0..255) + build_w2 (256..511) + zero_cnt (512..519) ---
__global__ __launch_bounds__(256) void k_prep3(
    const float* __restrict__ tw, const float* __restrict__ cw,
    float* __restrict__ ws) {
  int bid = blockIdx.x, c = threadIdx.x;
  __shared__ float zs[4][260];
  __shared__ float rA[DD], rB[DD], rC[DD];
  if (bid < 256) {
    int r0 = bid * 2;
    int b = r0 >> 6, l = r0 & 63;
    const float* zb = ws + WS_ZEU3 + (size_t)b * 64 * DD;
    float* zout = ws + WS_XSA1;
#pragma unroll
    for (int j = 0; j < 4; ++j) {
      int ll = (l + j - 1 + 64) & 63;
      zs[j][c] = zb[ll * DD + c];
    }
    __syncthreads();
    const float4* wA = (const float4*)(ws + WS_TWT + (size_t)c * DD);
    const float4* wB = (const float4*)(tw + (size_t)c * DD);
    const float4* wC = (const float4*)(ws + WS_CWT + (size_t)c * DD);
    const float4* zm0 = (const float4*)&zs[0][0];
    const float4* z00 = (const float4*)&zs[1][0];
    const float4* zp0 = (const float4*)&zs[2][0];
    const float4* zp1 = (const float4*)&zs[3][0];
    float a0 = 0.f, a1 = 0.f;
#pragma unroll 8
    for (int k4 = 0; k4 < 64; ++k4) {
      float4 A4 = wA[k4], B4 = wB[k4], C4 = wC[k4];
      float4 m0 = zm0[k4], z0 = z00[k4], p0 = zp0[k4], p1 = zp1[k4];
      a0 += m0.x*A4.x + m0.y*A4.y + m0.z*A4.z + m0.w*A4.w
          + p0.x*B4.x + p0.y*B4.y + p0.z*B4.z + p0.w*B4.w
          + z0.x*C4.x + z0.y*C4.y + z0.z*C4.z + z0.w*C4.w;
      a1 += z0.x*A4.x + z0.y*A4.y + z0.z*A4.z + z0.w*A4.w
          + p1.x*B4.x + p1.y*B4.y + p1.z*B4.z + p1.w*B4.w
          + p0.x*C4.x + p0.y*C4.y + p0.z*C4.z + p0.w*C4.w;
    }
    const float inv3 = 1.0f / 3.0f;
    zout[(size_t)r0 * DD + c]       = a0 * inv3 + zs[1][c];
    zout[(size_t)(r0 + 1) * DD + c] = a1 * inv3 + zs[2][c];
  } else if (bid < 512) {
    int k = bid - 256;
    const float* twT = ws + WS_TWT;
    const float inv9 = 1.0f / 9.0f;
    rA[c] = tw[k * DD + c] * inv9;
    rB[c] = twT[k * DD + c] * inv9;
    rC[c] = cw[k * DD + c] * inv9;
    __syncthreads();
    float a2 = 0.f, m1 = 0.f, m0 = 0.f, m3 = 0.f, b2 = 0.f;
#pragma unroll 4
    for (int j = 0; j < DD; ++j) {
      float Aj = tw[j * DD + c];
      float Bj = twT[j * DD + c];
      float Cj = cw[j * DD + c];
      float ra = rA[j], rb = rB[j], rc = rC[j];
      a2 += ra * Aj;
      m1 += rc * Aj + ra * Cj;
      m0 += rb * Aj + ra * Bj + rc * Cj;
      m3 += rc * Bj + rb * Cj;
      b2 += rb * Bj;
    }
    float* p0 = ws + WS_WCT;
    float* p3 = ws + WS_ZEU3;
    p0[k * DD + c]               = a2;
    p0[65536 + k * DD + c]       = m1;
    p0[2 * 65536 + k * DD + c]   = m0;
    p3[k * DD + c]               = m3;
    p3[65536 + k * DD + c]       = b2;
  } else {
    ((int*)(ws + WS_TOKS))[(bid - 512) * 256 + c] = 0;
  }
}

// --- scan_big: scan+emit (0..511) | head-ZE extras (512..1023, big mode) -
// Scan: 32 squared steps, 8 rows x 32 cols/block, W (K=1280) in 40 f32x4.
// Head-ZE extras depend only on ZE + eh/el (ready pre-launch), never wait
// -> deadlock-free under any dispatch order; they fill the 3rd block/CU
// slot (LDS 51200B -> 3/CU) and hide under the scan's sync stalls.
__global__ __launch_bounds__(256, 2) void k_scan_big(
    float* __restrict__ ws, const float* __restrict__ emiw,
    const float* __restrict__ emib, const unsigned short* __restrict__ eh,
    const unsigned short* __restrict__ el, float* __restrict__ hpart) {
  const int bid = blockIdx.x;
  const int t = threadIdx.x, lane = t & 63;

  __shared__ float SH[12800];   // scan: S|PAR|PAR2|ZB ; head: UH|UL

  if (bid >= 512) {             // ---- head-ZE role (big mode only) ----
    int eb = bid - 512;
    int row0 = RR + (eb & 15) * 32;
    int vy = eb >> 4;
    head_tile(row0, vy, ws + WS_EMIT, ws + WS_ZE, eh, el, hpart, SH, t);
    return;
  }

  float* S    = SH;             // 12*264 = 3168
  float* PAR  = SH + 3168;      // 32*260 = 8320
  float* PAR2 = SH + 11488;     // 1024
  float* ZB   = SH + 12512;     // 256

  const int rg = bid & 63, cg = bid >> 6;
  const int b = rg >> 3, rgl = rg & 7, l0 = rgl * 8;
  const int cl = t & 7, rs = t >> 3;
  const int c0 = cg * 32 + cl * 4;

  int* tok = (int*)(ws + WS_TOKS);

  const float* Wp[5] = {ws + WS_WCT, ws + WS_WCT + 65536, ws + WS_WCT + 2*65536,
                        ws + WS_ZEU3, ws + WS_ZEU3 + 65536};
  f32x4 wreg[40];
#pragma unroll
  for (int p = 0; p < 5; ++p)
#pragma unroll
    for (int q = 0; q < 2; ++q)
#pragma unroll
      for (int kk = 0; kk < 4; ++kk)
        wreg[p * 8 + q * 4 + kk] =
            *(const f32x4*)&Wp[p][(size_t)(rs * 8 + q * 4 + kk) * DD + c0];

  { // z2 tile from XSA1 (pre-scan by prep3-zmat2)
    int r = t >> 5, c = t & 31;
    ZB[r * 32 + c] = ws[WS_XSA1 + (size_t)(b * 64 + l0 + r) * DD + cg * 32 + c];
  }

  const int nb0 = b * 8 + ((rgl + 7) & 7);
  const int nb1 = b * 8 + rgl;
  const int nb2 = b * 8 + ((rgl + 1) & 7);
  const int myl = (lane == 0) ? nb0 : (lane == 1) ? nb1 : nb2;

  for (int st = 0; st < 32; ++st) {
    const float* xin  = ws + ((st & 1) ? WS_XSA1 : WS_XSA0);
    float*       xout = ws + ((st & 1) ? WS_XSA0 : WS_XSA1);

    if (st > 0) {
      const int tg = st << 3;
      while (true) {
        int v = __hip_atomic_load(tok + myl * 32, __ATOMIC_RELAXED,
                                  __HIP_MEMORY_SCOPE_AGENT);
        if (__all(v >= tg)) break;
        __builtin_amdgcn_s_sleep(1);
      }
    }

#pragma unroll
    for (int it = 0; it < 6; ++it) {
      int idx = it * 256 + t;
      int j = idx >> 7;
      int kk = (idx & 127) << 1;
      const u64* src = (st == 0)
          ? (const u64*)(ws + WS_X0VEC + kk)
          : (const u64*)(xin + (size_t)(b * 64 + ((l0 + j - 2 + 64) & 63)) * DD + kk);
      u64 v = __hip_atomic_load(src, __ATOMIC_RELAXED, __HIP_MEMORY_SCOPE_AGENT);
      *(u64*)(&S[j * 264 + kk]) = v;
    }
    __syncthreads();

    f32x4 acc[8];
#pragma unroll
    for (int r = 0; r < 8; ++r) acc[r] = (f32x4){0.f, 0.f, 0.f, 0.f};

#pragma unroll
    for (int p = 0; p < 5; ++p) {
#pragma unroll
      for (int r = 0; r < 8; ++r) {
        int j = r + p;
#pragma unroll
        for (int q = 0; q < 2; ++q) {
          f32x4 xv = *(const f32x4*)&S[j * 264 + rs * 8 + q * 4];
          acc[r] += xv.x * wreg[p * 8 + q * 4 + 0];
          acc[r] += xv.y * wreg[p * 8 + q * 4 + 1];
          acc[r] += xv.z * wreg[p * 8 + q * 4 + 2];
          acc[r] += xv.w * wreg[p * 8 + q * 4 + 3];
        }
      }
    }

#pragma unroll
    for (int r = 0; r < 8; ++r)
      *(f32x4*)&PAR[rs * 260 + r * 32 + cl * 4] = acc[r];
    __syncthreads();

    {
      int u = t & 63, v = t >> 6;
      f32x4 s4 = (f32x4){0.f, 0.f, 0.f, 0.f};
#pragma unroll
      for (int i = 0; i < 8; ++i)
        s4 += *(const f32x4*)&PAR[(v * 8 + i) * 260 + u * 4];
      *(f32x4*)&PAR2[v * 256 + u * 4] = s4;
    }
    __syncthreads();

    if (t < 64) {
      int r = t >> 3, c8 = t & 7;
      f32x4 s4 = (f32x4){0.f, 0.f, 0.f, 0.f};
#pragma unroll
      for (int v = 0; v < 4; ++v)
        s4 += *(const f32x4*)&PAR2[v * 256 + t * 4];
      f32x4 zb = *(const f32x4*)&ZB[r * 32 + c8 * 4];
      s4 += zb;
      size_t off = (size_t)(b * 64 + l0 + r) * DD + cg * 32 + c8 * 4;
      U64F2 lo, hi;
      lo.f[0] = s4.x; lo.f[1] = s4.y;
      hi.f[0] = s4.z; hi.f[1] = s4.w;
      __hip_atomic_store((u64*)(xout + off),     lo.u, __ATOMIC_RELAXED, __HIP_MEMORY_SCOPE_AGENT);
      __hip_atomic_store((u64*)(xout + off + 2), hi.u, __ATOMIC_RELAXED, __HIP_MEMORY_SCOPE_AGENT);
    }

    __syncthreads();   // drains vmcnt(0): bypass stores visible first
    if (t == 0)
      __hip_atomic_fetch_add(tok + nb1 * 32, 1, __ATOMIC_RELAXED,
                             __HIP_MEMORY_SCOPE_AGENT);
  }

  // ---- emit tail: wait own rowgroup done, then 8 rows x 32 cols of emit --
  if (t == 0) {
    while (__hip_atomic_load(tok + nb1 * 32, __ATOMIC_RELAXED,
                             __HIP_MEMORY_SCOPE_AGENT) < 256)
      __builtin_amdgcn_s_sleep(1);
  }
  __syncthreads();
#pragma unroll
  for (int it = 0; it < 4; ++it) {
    int idx = it * 256 + t;
    int j = idx >> 7;
    int kk = (idx & 127) << 1;
    u64 v = __hip_atomic_load(
        (const u64*)(ws + WS_XSA0 + (size_t)(b * 64 + l0 + j) * DD + kk),
        __ATOMIC_RELAXED, __HIP_MEMORY_SCOPE_AGENT);
    *(u64*)(&S[j * 264 + kk]) = v;
  }
  __syncthreads();
  {
    int r = t >> 5, c = cg * 32 + (t & 31);
    const float4* wv = (const float4*)(emiw + (size_t)c * DD);
    const float4* xv = (const float4*)&S[r * 264];
    float a = 0.f;
#pragma unroll 8
    for (int k4 = 0; k4 < 64; ++k4) {
      float4 w = wv[k4], x = xv[k4];
      a += x.x*w.x + x.y*w.y + x.z*w.z + x.w*w.w;
    }
    ws[WS_EMIT + (size_t)(b * 64 + l0 + r) * DD + c] = a + emib[c];
  }
}

// --- standalone head kernel (emit half in big mode; full grid otherwise) -
__global__ __launch_bounds__(256) void k_head_mfma(
    const float* __restrict__ uemit, const float* __restrict__ uze,
    const unsigned short* __restrict__ eh, const unsigned short* __restrict__ el,
    float* __restrict__ hpart) {
  __shared__ float SH[8448];
  head_tile(blockIdx.x * 32, blockIdx.y, uemit, uze, eh, el, hpart, SH,
            threadIdx.x);
}

// --- finish: yk + ylse + sel + tgt + comb + final, fused; grid(8) --------
__global__ __launch_bounds__(256) void k_finish(
    const int* __restrict__ x, const float* __restrict__ embed,
    const float* __restrict__ xks, const float* __restrict__ xkdw,
    const float* __restrict__ xkdb, float* __restrict__ ws,
    const float* __restrict__ hp, float* __restrict__ out) {
  int b = blockIdx.x, t = threadIdx.x, lane = t & 63, w = t >> 6;
  __shared__ float YK[DD];
  __shared__ float rm[4], rv[4];
  __shared__ float ylse_s;
  __shared__ float sel0[64], sel1[64], sel2[64], tg0[64], tg1[64];
  __shared__ float ls0s[64], ls1s[64];

  {
    float acc = xkdb[t];
    const float4* yv4 = (const float4*)(ws + WS_YVEC);
    const float4* w4 = (const float4*)(xkdw + (size_t)t * DD);
    float a = 0.f;
#pragma unroll 8
    for (int k4 = 0; k4 < 64; ++k4) {
      float4 yv = yv4[k4], wv = w4[k4];
      a += yv.x*wv.x + yv.y*wv.y + yv.z*wv.z + yv.w*wv.w;
    }
    YK[t] = acc + a;
  }
  {
    float m = -1e30f, s = 0.f;
    for (int v = t; v < VV; v += 256) {
      float lg = ws[WS_YLOG + v];
      float mn = fmaxf(m, lg);
      s = s * __expf(m - mn) + __expf(lg - mn);
      m = mn;
    }
#pragma unroll
    for (int o = 32; o > 0; o >>= 1) {
      float mo = __shfl_xor(m, o, 64), so = __shfl_xor(s, o, 64);
      float mn = fmaxf(m, mo);
      s = s * __expf(m - mn) + so * __expf(mo - mn);
      m = mn;
    }
    if (lane == 0) { rm[w] = m; rv[w] = s; }
  }
  __syncthreads();
  if (t == 0) {
    float M = fmaxf(fmaxf(rm[0], rm[1]), fmaxf(rm[2], rm[3]));
    float S = rv[0]*__expf(rm[0]-M) + rv[1]*__expf(rm[1]-M) +
              rv[2]*__expf(rm[2]-M) + rv[3]*__expf(rm[3]-M);
    ylse_s = M + logf(S);
  }

  for (int i = 0; i < 16; ++i) {
    int l = w * 16 + i, r = b * 64 + l;
    float4 xs = *(const float4*)&ws[WS_XSA0 + (size_t)r * DD + lane * 4];
    float4 k0 = *(const float4*)&xks[lane * 4];
    float4 k1 = *(const float4*)&xks[DD + lane * 4];
    float4 yk4 = *(const float4*)&YK[lane * 4];
    float s0 = waveSum(xs.x*k0.x + xs.y*k0.y + xs.z*k0.z + xs.w*k0.w);
    float s1 = waveSum(xs.x*k1.x + xs.y*k1.y + xs.z*k1.z + xs.w*k1.w);
    float s2 = waveSum(xs.x*yk4.x + xs.y*yk4.y + xs.z*yk4.z + xs.w*yk4.w);
    int xv = x[r];
    float4 e4 = *(const float4*)&embed[(size_t)xv * DD + lane * 4];
    float4 em = *(const float4*)&ws[WS_EMIT + (size_t)r * DD + lane * 4];
    float4 zr = *(const float4*)&ws[WS_ZE + (size_t)r * DD + lane * 4];
    float t0 = waveSum(em.x*e4.x + em.y*e4.y + em.z*e4.z + em.w*e4.w);
    float t1 = waveSum(zr.x*e4.x + zr.y*e4.y + zr.z*e4.z + zr.w*e4.w);
    float m0 = hp[((size_t)r * 64 + lane) * 2];
    float q0 = hp[((size_t)r * 64 + lane) * 2 + 1];
    float m1 = hp[((size_t)(RR + r) * 64 + lane) * 2];
    float q1 = hp[((size_t)(RR + r) * 64 + lane) * 2 + 1];
#pragma unroll
    for (int o = 32; o > 0; o >>= 1) {
      float mo = __shfl_xor(m0, o, 64), so = __shfl_xor(q0, o, 64);
      float mn = fmaxf(m0, mo);
      q0 = q0 * __expf(m0 - mn) + so * __expf(mo - mn);
      m0 = mn;
      mo = __shfl_xor(m1, o, 64); so = __shfl_xor(q1, o, 64);
      mn = fmaxf(m1, mo);
      q1 = q1 * __expf(m1 - mn) + so * __expf(mo - mn);
      m1 = mn;
    }
    if (lane == 0) {
      sel0[l] = s0; sel1[l] = s1; sel2[l] = s2;
      tg0[l] = t0; tg1[l] = t1;
      ls0s[l] = m0 + logf(q0);
      ls1s[l] = m1 + logf(q1);
    }
  }
  __syncthreads();
  if (w == 0) {
    int l = lane, r = b * 64 + l;
    float s0 = sel0[l], s1 = sel1[l], s2 = sel2[l];
    float mx = fmaxf(s0, fmaxf(s1, s2));
    float den = expf(s0 - mx) + expf(s1 - mx) + 64.f * expf(s2 - mx);
    float lsel = mx + logf(den);
    int xv = x[r];
    float P0 = expf(s0 - lsel + tg0[l] - ls0s[l]);
    float P1 = expf(s1 - lsel + tg1[l] - ls1s[l]);
    float Py = expf(s2 - lsel + ws[WS_YLOG + xv] - ylse_s);
    float cent = sqrtf(P0 + P1 + 64.f * Py);
    float sum = waveSum(cent);
    if (lane == 0) out[b] = -(sum * (1.0f / 64.f));
  }
}

extern "C" void kernel_launch(void* const* d_in, const int* in_sizes, int n_in,
                              void* d_out, int out_size, void* d_ws, size_t ws_size,
                              hipStream_t stream) {
  (void)in_sizes; (void)n_in; (void)out_size;
  const int*   x     = (const int*)d_in[0];
  const int*   z     = (const int*)d_in[1];
  const float* embed = (const float*)d_in[2];
  const float* initw = (const float*)d_in[3];
  const float* tw    = (const float*)d_in[4];
  const float* tb    = (const float*)d_in[5];
  const float* cw    = (const float*)d_in[6];
  const float* uw    = (const float*)d_in[7];
  const float* xks   = (const float*)d_in[8];
  const float* xkdw  = (const float*)d_in[9];
  const float* xkdb  = (const float*)d_in[10];
  const float* emiw  = (const float*)d_in[11];
  const float* emib  = (const float*)d_in[12];
  float* ws  = (float*)d_ws;
  float* out = (float*)d_out;

  const bool big = ws_size >= (size_t)WS_BIG_FLOATS * sizeof(float);
  float* hpart = ws + (big ? WS_HPHI : WS_WCT);
  const unsigned short* ehg = (const unsigned short*)(ws + WS_EHI);
  const unsigned short* elg = (const unsigned short*)(ws + WS_ELO);

  // P0: yvec/x0vec (so prep1's ylog role has yvec)
  hipLaunchKernelGGL(k_prep0, dim3(2), dim3(256), 0, stream, embed, initw, ws);
  // P1: ze-norm + transposes + split_e + ylog (independent roles)
  hipLaunchKernelGGL(k_prep1, dim3(RR + 2 + 256 + 1024 + 64), dim3(256), 0,
                     stream, z, embed, initw, tw, cw, ws);
  // P2: zeu3 = (ze @ uw^T + tb)/3
  hipLaunchKernelGGL(k_rowmat2, dim3(256), dim3(256), 0, stream,
                     ws + WS_ZE, uw, tb, ws + WS_ZEU3, 1.0f / 3.0f);
  // P3: z2 + squared-operator matrices + token zero
  hipLaunchKernelGGL(k_prep3, dim3(520), dim3(256), 0, stream, tw, cw, ws);
  // SCAN + emit tail (+ hidden head-ZE extras in big mode)
  hipLaunchKernelGGL(k_scan_big, dim3(big ? 1024 : 512), dim3(256), 0, stream,
                     ws, emiw, emib, ehg, elg, hpart);
  // Head: emit half (big) or full (fallback)
  hipLaunchKernelGGL(k_head_mfma, dim3(big ? 16 : 32, 32), dim3(256), 0, stream,
                     ws + WS_EMIT, ws + WS_ZE, ehg, elg, hpart);
  hipLaunchKernelGGL(k_finish, dim3(8), dim3(256), 0, stream,
                     x, embed, xks, xkdw, xkdb, ws, hpart, out);
}